// Round 2
// baseline (296.310 us; speedup 1.0000x reference)
//
#include <hip/hip_runtime.h>
#include <cstdint>
#include <cstddef>

#define SLEN 2048
#define DH   64
#define NQT  32          // SLEN / QBLK
#define QBLK 64
#define KVB  64
#define LOG2E 1.44269504088896340736f

typedef short  bf16x8 __attribute__((ext_vector_type(8)));
typedef float  f32x4  __attribute__((ext_vector_type(4)));

__device__ __forceinline__ unsigned short f2bf(float f) {
    union { float f; unsigned int u; } v;
    v.f = f;
    unsigned int u = v.u;
    u += 0x7FFFu + ((u >> 16) & 1u);   // round-to-nearest-even
    return (unsigned short)(u >> 16);
}

// One block = 64 q-rows of one (b,h); 4 waves x 16 rows each.
// Flash attention, causal. Scale (1/sqrt(D))*log2(e) folded into Q so softmax
// uses exp2. Global-max subtraction in the reference cancels mathematically.
__global__ __launch_bounds__(256) void fattn(const float* __restrict__ Qg,
                                             const float* __restrict__ Kg,
                                             const float* __restrict__ Vg,
                                             float* __restrict__ Og)
{
    // K tile: bf16 row-major [k][d], byte ^= ((row&7)<<4) swizzle
    __shared__ __attribute__((aligned(16))) unsigned short Klds[KVB * DH];
    // V tile: bf16 TRANSPOSED [d][k], same swizzle (row = d)
    __shared__ __attribute__((aligned(16))) unsigned short Vlds[DH * KVB];
    // P tile per wave: bf16 [q][k], same swizzle (row = q-local)
    __shared__ __attribute__((aligned(16))) unsigned short Plds[4][16 * KVB];

    const int bid = blockIdx.x;
    const int qt  = bid & (NQT - 1);
    const int bh  = bid >> 5;
    const int qb  = qt * QBLK;

    const float* Qp = Qg + (size_t)bh * SLEN * DH;
    const float* Kp = Kg + (size_t)bh * SLEN * DH;
    const float* Vp = Vg + (size_t)bh * SLEN * DH;
    float*       Op = Og + (size_t)bh * SLEN * DH;

    const int tid  = threadIdx.x;
    const int w    = tid >> 6;
    const int lane = tid & 63;
    const int g    = lane >> 4;
    const int m    = lane & 15;

    // ---- Q fragments: A-frag row = m, k(d) = 8g + 32c + j (contiguous 8) ----
    bf16x8 qf[2];
    {
        const float sc = 0.125f * LOG2E;
        const int qrow = qb + 16 * w + m;
        #pragma unroll
        for (int c = 0; c < 2; ++c) {
            const float* src = Qp + (size_t)qrow * DH + 32 * c + 8 * g;
            float4 a = *reinterpret_cast<const float4*>(src);
            float4 b = *reinterpret_cast<const float4*>(src + 4);
            bf16x8 q;
            q[0] = (short)f2bf(a.x * sc); q[1] = (short)f2bf(a.y * sc);
            q[2] = (short)f2bf(a.z * sc); q[3] = (short)f2bf(a.w * sc);
            q[4] = (short)f2bf(b.x * sc); q[5] = (short)f2bf(b.y * sc);
            q[6] = (short)f2bf(b.z * sc); q[7] = (short)f2bf(b.w * sc);
            qf[c] = q;
        }
    }

    f32x4 o[4];
    #pragma unroll
    for (int dt = 0; dt < 4; ++dt) o[dt] = (f32x4){0.f, 0.f, 0.f, 0.f};
    float mrun[4], lrun[4];
    #pragma unroll
    for (int r = 0; r < 4; ++r) { mrun[r] = -1e30f; lrun[r] = 0.f; }

    const int sr = tid & 63;   // staging: row within KV tile
    const int sq = tid >> 6;   // staging: 16-col group
    const int nt = qt + 1;

    unsigned short* Pw = &Plds[w][0];

    for (int jt = 0; jt < nt; ++jt) {
        const int kvb = jt * KVB;
        const bool diag = (jt == qt);

        __syncthreads();   // previous iteration's LDS reads done

        // ---- stage K tile ----
        {
            const float* src = Kp + (size_t)(kvb + sr) * DH + 16 * sq;
            float4 x0 = *reinterpret_cast<const float4*>(src + 0);
            float4 x1 = *reinterpret_cast<const float4*>(src + 4);
            float4 x2 = *reinterpret_cast<const float4*>(src + 8);
            float4 x3 = *reinterpret_cast<const float4*>(src + 12);
            bf16x8 lo, hi;
            lo[0] = (short)f2bf(x0.x); lo[1] = (short)f2bf(x0.y);
            lo[2] = (short)f2bf(x0.z); lo[3] = (short)f2bf(x0.w);
            lo[4] = (short)f2bf(x1.x); lo[5] = (short)f2bf(x1.y);
            lo[6] = (short)f2bf(x1.z); lo[7] = (short)f2bf(x1.w);
            hi[0] = (short)f2bf(x2.x); hi[1] = (short)f2bf(x2.y);
            hi[2] = (short)f2bf(x2.z); hi[3] = (short)f2bf(x2.w);
            hi[4] = (short)f2bf(x3.x); hi[5] = (short)f2bf(x3.y);
            hi[6] = (short)f2bf(x3.z); hi[7] = (short)f2bf(x3.w);
            const unsigned int base = (unsigned)(sr * 128 + 32 * sq);
            const unsigned int swz  = ((unsigned)(sr & 7)) << 4;
            *(bf16x8*)((char*)Klds + (base ^ swz))        = lo;
            *(bf16x8*)((char*)Klds + ((base + 16) ^ swz)) = hi;
        }
        // ---- stage V tile transposed: Vlds[d][k] = V[kvb+k][d] ----
        {
            const float* src = Vp + (size_t)(kvb + sr) * DH + 16 * sq;
            float4 x0 = *reinterpret_cast<const float4*>(src + 0);
            float4 x1 = *reinterpret_cast<const float4*>(src + 4);
            float4 x2 = *reinterpret_cast<const float4*>(src + 8);
            float4 x3 = *reinterpret_cast<const float4*>(src + 12);
            unsigned short t16[16];
            t16[0]  = f2bf(x0.x); t16[1]  = f2bf(x0.y); t16[2]  = f2bf(x0.z); t16[3]  = f2bf(x0.w);
            t16[4]  = f2bf(x1.x); t16[5]  = f2bf(x1.y); t16[6]  = f2bf(x1.z); t16[7]  = f2bf(x1.w);
            t16[8]  = f2bf(x2.x); t16[9]  = f2bf(x2.y); t16[10] = f2bf(x2.z); t16[11] = f2bf(x2.w);
            t16[12] = f2bf(x3.x); t16[13] = f2bf(x3.y); t16[14] = f2bf(x3.z); t16[15] = f2bf(x3.w);
            #pragma unroll
            for (int j = 0; j < 16; ++j) {
                const int d = 16 * sq + j;
                const unsigned int byte =
                    ((unsigned)(d * 128 + 2 * sr)) ^ (((unsigned)(d & 7)) << 4);
                *(unsigned short*)((char*)Vlds + byte) = t16[j];
            }
        }
        __syncthreads();

        // ---- QK^T: S[16q x 64k] per wave = 4 col-tiles x (K=64 -> 2 mfma) ----
        f32x4 s[4];
        #pragma unroll
        for (int t = 0; t < 4; ++t) s[t] = (f32x4){0.f, 0.f, 0.f, 0.f};
        #pragma unroll
        for (int c = 0; c < 2; ++c) {
            #pragma unroll
            for (int t = 0; t < 4; ++t) {
                const unsigned int row  = (unsigned)(16 * t + m);
                const unsigned int byte =
                    (row * 128u + (unsigned)(32 * c + 8 * g) * 2u) ^ ((row & 7u) << 4);
                bf16x8 kf = *(const bf16x8*)((const char*)Klds + byte);
                s[t] = __builtin_amdgcn_mfma_f32_16x16x32_bf16(qf[c], kf, s[t], 0, 0, 0);
            }
        }

        // ---- mask + online softmax.  C-layout: row = 4g+reg, col = 16t+m ----
        float p[4][4];   // [t][reg]
        #pragma unroll
        for (int reg = 0; reg < 4; ++reg) {
            const int qrow = qb + 16 * w + 4 * g + reg;
            float x0 = s[0][reg], x1 = s[1][reg], x2 = s[2][reg], x3 = s[3][reg];
            if (diag) {
                const int colb = kvb + m;
                x0 = (colb      > qrow) ? -1e30f : x0;
                x1 = (colb + 16 > qrow) ? -1e30f : x1;
                x2 = (colb + 32 > qrow) ? -1e30f : x2;
                x3 = (colb + 48 > qrow) ? -1e30f : x3;
            }
            float mx = fmaxf(fmaxf(x0, x1), fmaxf(x2, x3));
            #pragma unroll
            for (int d = 1; d < 16; d <<= 1) mx = fmaxf(mx, __shfl_xor(mx, d));
            const float mnew = fmaxf(mrun[reg], mx);
            const float fs   = exp2f(mrun[reg] - mnew);
            mrun[reg] = mnew;
            const float p0 = exp2f(x0 - mnew);
            const float p1 = exp2f(x1 - mnew);
            const float p2 = exp2f(x2 - mnew);
            const float p3 = exp2f(x3 - mnew);
            p[0][reg] = p0; p[1][reg] = p1; p[2][reg] = p2; p[3][reg] = p3;
            float ps = p0 + p1 + p2 + p3;
            #pragma unroll
            for (int d = 1; d < 16; d <<= 1) ps += __shfl_xor(ps, d);
            lrun[reg] = lrun[reg] * fs + ps;
            o[0][reg] *= fs; o[1][reg] *= fs; o[2][reg] *= fs; o[3][reg] *= fs;
        }

        // ---- P -> per-wave LDS (bf16, swizzled) ----
        #pragma unroll
        for (int t = 0; t < 4; ++t) {
            #pragma unroll
            for (int reg = 0; reg < 4; ++reg) {
                const unsigned int row  = (unsigned)(4 * g + reg);
                const unsigned int byte =
                    (row * 128u + (unsigned)(16 * t + m) * 2u) ^ ((row & 7u) << 4);
                *(unsigned short*)((char*)Pw + byte) = f2bf(p[t][reg]);
            }
        }
        asm volatile("s_waitcnt lgkmcnt(0)" ::: "memory");

        // ---- PV: O[16q x 64d] += P[16 x 64] * V[64 x 64] ----
        #pragma unroll
        for (int kc = 0; kc < 2; ++kc) {
            const unsigned int arow = (unsigned)m;
            const unsigned int ab   =
                (arow * 128u + (unsigned)(32 * kc + 8 * g) * 2u) ^ ((arow & 7u) << 4);
            bf16x8 pa = *(const bf16x8*)((const char*)Pw + ab);
            #pragma unroll
            for (int dt = 0; dt < 4; ++dt) {
                const unsigned int d  = (unsigned)(16 * dt + m);
                const unsigned int vb =
                    (d * 128u + (unsigned)(32 * kc + 8 * g) * 2u) ^ ((d & 7u) << 4);
                bf16x8 vf = *(const bf16x8*)((const char*)Vlds + vb);
                o[dt] = __builtin_amdgcn_mfma_f32_16x16x32_bf16(pa, vf, o[dt], 0, 0, 0);
            }
        }
    }

    // ---- epilogue: normalize by row-sum and store fp32 ----
    float inv[4];
    #pragma unroll
    for (int reg = 0; reg < 4; ++reg) inv[reg] = 1.0f / lrun[reg];
    #pragma unroll
    for (int reg = 0; reg < 4; ++reg) {
        const int qrow = qb + 16 * w + 4 * g + reg;
        float* dst = Op + (size_t)qrow * DH;
        #pragma unroll
        for (int dt = 0; dt < 4; ++dt) dst[16 * dt + m] = o[dt][reg] * inv[reg];
    }
}

extern "C" void kernel_launch(void* const* d_in, const int* in_sizes, int n_in,
                              void* d_out, int out_size, void* d_ws, size_t ws_size,
                              hipStream_t stream) {
    const float* Q = (const float*)d_in[0];
    const float* K = (const float*)d_in[1];
    const float* V = (const float*)d_in[2];
    float* O = (float*)d_out;
    dim3 grid(2 * 16 * NQT);   // B*H * (S/QBLK) = 1024
    dim3 block(256);
    fattn<<<grid, block, 0, stream>>>(Q, K, V, O);
}

// Round 3
// 269.828 us; speedup vs baseline: 1.0981x; 1.0981x over previous
//
#include <hip/hip_runtime.h>
#include <hip/hip_bf16.h>
#include <cstdint>
#include <cstddef>

#define SLEN 2048
#define DH   64
#define NQT  32          // SLEN / QBLK
#define QBLK 64
#define KVB  64
#define LOG2E 1.44269504088896340736f

typedef short  bf16x8 __attribute__((ext_vector_type(8)));
typedef float  f32x4  __attribute__((ext_vector_type(4)));

__device__ __forceinline__ unsigned short f2bf(float f) {
    __hip_bfloat16 h = __float2bfloat16(f);   // compiler lowers to cvt_pk pairs
    return *reinterpret_cast<unsigned short*>(&h);
}

// One block = 64 q-rows of one (b,h); 4 waves x 16 rows each.
// Flash attention, causal. Scale (1/sqrt(D))*log2(e) folded into Q so softmax
// uses exp2. Global-max subtraction in the reference cancels mathematically.
//
// bid -> (bh, qt) XOR-balanced: co-resident blocks (stride 256 across CUs)
// get qt sets {q, q^31, q^16, q^15} whose work sums to a constant 66 tiles.
// K/V double-buffered in LDS; next tile's global loads issued right after the
// single per-iteration barrier so HBM latency hides under compute (T14).
__global__ __launch_bounds__(256) void fattn(const float* __restrict__ Qg,
                                             const float* __restrict__ Kg,
                                             const float* __restrict__ Vg,
                                             float* __restrict__ Og)
{
    // K tile: bf16 row-major [k][d], byte ^= ((row&7)<<4) swizzle
    __shared__ __attribute__((aligned(16))) unsigned short Klds[2][KVB * DH];
    // V tile: bf16 TRANSPOSED [d][k], same swizzle (row = d)
    __shared__ __attribute__((aligned(16))) unsigned short Vlds[2][DH * KVB];
    // P tile per wave: bf16 [q][k], same swizzle (row = q-local)
    __shared__ __attribute__((aligned(16))) unsigned short Plds[4][16 * KVB];

    const int bid = blockIdx.x;
    const int hi4 = bid >> 8;          // 0..3
    const int lo8 = bid & 255;
    const int qx  = (int)((0x0F101F00u >> (8 * hi4)) & 31u);  // {0,31,16,15}
    const int qt  = (lo8 & 31) ^ qx;
    const int bh  = (hi4 << 3) | (lo8 >> 5);
    const int qb  = qt * QBLK;

    const float* Qp = Qg + (size_t)bh * SLEN * DH;
    const float* Kp = Kg + (size_t)bh * SLEN * DH;
    const float* Vp = Vg + (size_t)bh * SLEN * DH;
    float*       Op = Og + (size_t)bh * SLEN * DH;

    const int tid  = threadIdx.x;
    const int w    = tid >> 6;
    const int lane = tid & 63;
    const int g    = lane >> 4;
    const int m    = lane & 15;

    // ---- Q fragments: A-frag row = m, k(d) = 8g + 32c + j (contiguous 8) ----
    bf16x8 qf[2];
    {
        const float sc = 0.125f * LOG2E;
        const int qrow = qb + 16 * w + m;
        #pragma unroll
        for (int c = 0; c < 2; ++c) {
            const float* src = Qp + (size_t)qrow * DH + 32 * c + 8 * g;
            float4 a = *reinterpret_cast<const float4*>(src);
            float4 b = *reinterpret_cast<const float4*>(src + 4);
            bf16x8 q;
            q[0] = (short)f2bf(a.x * sc); q[1] = (short)f2bf(a.y * sc);
            q[2] = (short)f2bf(a.z * sc); q[3] = (short)f2bf(a.w * sc);
            q[4] = (short)f2bf(b.x * sc); q[5] = (short)f2bf(b.y * sc);
            q[6] = (short)f2bf(b.z * sc); q[7] = (short)f2bf(b.w * sc);
            qf[c] = q;
        }
    }

    f32x4 o[4];
    #pragma unroll
    for (int dt = 0; dt < 4; ++dt) o[dt] = (f32x4){0.f, 0.f, 0.f, 0.f};
    float mrun[4], lrun[4];
    #pragma unroll
    for (int r = 0; r < 4; ++r) { mrun[r] = -1e30f; lrun[r] = 0.f; }

    const int sr = tid & 63;   // staging: row within KV tile
    const int sq = tid >> 6;   // staging: 16-col group
    const int nt = qt + 1;

    unsigned short* Pw = &Plds[w][0];

    // ---- prefetch registers (fp32, one KV row-chunk per thread) ----
    float4 ka, kb, kc, kd, va, vb, vc, vd;
    const float* Ks = Kp + (size_t)sr * DH + 16 * sq;
    const float* Vs = Vp + (size_t)sr * DH + 16 * sq;

    #define ISSUE(jt_)                                                         \
        do {                                                                   \
            const float* ks_ = Ks + (size_t)(jt_) * (KVB * DH);                \
            ka = *reinterpret_cast<const float4*>(ks_ + 0);                    \
            kb = *reinterpret_cast<const float4*>(ks_ + 4);                    \
            kc = *reinterpret_cast<const float4*>(ks_ + 8);                    \
            kd = *reinterpret_cast<const float4*>(ks_ + 12);                   \
            const float* vs_ = Vs + (size_t)(jt_) * (KVB * DH);                \
            va = *reinterpret_cast<const float4*>(vs_ + 0);                    \
            vb = *reinterpret_cast<const float4*>(vs_ + 4);                    \
            vc = *reinterpret_cast<const float4*>(vs_ + 8);                    \
            vd = *reinterpret_cast<const float4*>(vs_ + 12);                   \
        } while (0)

    ISSUE(0);

    for (int jt = 0; jt < nt; ++jt) {
        const int kvb  = jt * KVB;
        const bool diag = (jt == qt);
        const int buf  = jt & 1;
        unsigned short* Kb = &Klds[buf][0];
        unsigned short* Vb = &Vlds[buf][0];

        // ---- convert prefetched regs -> LDS (bf16, swizzled) ----
        {
            bf16x8 lo, hi;
            lo[0] = (short)f2bf(ka.x); lo[1] = (short)f2bf(ka.y);
            lo[2] = (short)f2bf(ka.z); lo[3] = (short)f2bf(ka.w);
            lo[4] = (short)f2bf(kb.x); lo[5] = (short)f2bf(kb.y);
            lo[6] = (short)f2bf(kb.z); lo[7] = (short)f2bf(kb.w);
            hi[0] = (short)f2bf(kc.x); hi[1] = (short)f2bf(kc.y);
            hi[2] = (short)f2bf(kc.z); hi[3] = (short)f2bf(kc.w);
            hi[4] = (short)f2bf(kd.x); hi[5] = (short)f2bf(kd.y);
            hi[6] = (short)f2bf(kd.z); hi[7] = (short)f2bf(kd.w);
            const unsigned int base = (unsigned)(sr * 128 + 32 * sq);
            const unsigned int swz  = ((unsigned)(sr & 7)) << 4;
            *(bf16x8*)((char*)Kb + (base ^ swz))        = lo;
            *(bf16x8*)((char*)Kb + ((base + 16) ^ swz)) = hi;

            unsigned short t16[16];
            t16[0]  = f2bf(va.x); t16[1]  = f2bf(va.y); t16[2]  = f2bf(va.z); t16[3]  = f2bf(va.w);
            t16[4]  = f2bf(vb.x); t16[5]  = f2bf(vb.y); t16[6]  = f2bf(vb.z); t16[7]  = f2bf(vb.w);
            t16[8]  = f2bf(vc.x); t16[9]  = f2bf(vc.y); t16[10] = f2bf(vc.z); t16[11] = f2bf(vc.w);
            t16[12] = f2bf(vd.x); t16[13] = f2bf(vd.y); t16[14] = f2bf(vd.z); t16[15] = f2bf(vd.w);
            #pragma unroll
            for (int j = 0; j < 16; ++j) {
                const int d = 16 * sq + j;
                const unsigned int byte =
                    ((unsigned)(d * 128 + 2 * sr)) ^ (((unsigned)(d & 7)) << 4);
                *(unsigned short*)((char*)Vb + byte) = t16[j];
            }
        }
        __syncthreads();   // staged tile visible; prev buf's readers done

        // ---- issue next tile's global loads (hide HBM under compute) ----
        if (jt + 1 < nt) ISSUE(jt + 1);

        // ---- QK^T: S[16q x 64k] per wave = 4 col-tiles x (K=64 -> 2 mfma) ----
        f32x4 s[4];
        #pragma unroll
        for (int t = 0; t < 4; ++t) s[t] = (f32x4){0.f, 0.f, 0.f, 0.f};
        #pragma unroll
        for (int c = 0; c < 2; ++c) {
            #pragma unroll
            for (int t = 0; t < 4; ++t) {
                const unsigned int row  = (unsigned)(16 * t + m);
                const unsigned int byte =
                    (row * 128u + (unsigned)(32 * c + 8 * g) * 2u) ^ ((row & 7u) << 4);
                bf16x8 kf = *(const bf16x8*)((const char*)Kb + byte);
                s[t] = __builtin_amdgcn_mfma_f32_16x16x32_bf16(qf[c], kf, s[t], 0, 0, 0);
            }
        }

        // ---- mask + online softmax.  C-layout: row = 4g+reg, col = 16t+m ----
        float p[4][4];   // [t][reg]
        #pragma unroll
        for (int reg = 0; reg < 4; ++reg) {
            const int qrow = qb + 16 * w + 4 * g + reg;
            float x0 = s[0][reg], x1 = s[1][reg], x2 = s[2][reg], x3 = s[3][reg];
            if (diag) {
                const int colb = kvb + m;
                x0 = (colb      > qrow) ? -1e30f : x0;
                x1 = (colb + 16 > qrow) ? -1e30f : x1;
                x2 = (colb + 32 > qrow) ? -1e30f : x2;
                x3 = (colb + 48 > qrow) ? -1e30f : x3;
            }
            float mx = fmaxf(fmaxf(x0, x1), fmaxf(x2, x3));
            #pragma unroll
            for (int d = 1; d < 16; d <<= 1) mx = fmaxf(mx, __shfl_xor(mx, d));
            const float mnew = fmaxf(mrun[reg], mx);
            const float fs   = exp2f(mrun[reg] - mnew);
            mrun[reg] = mnew;
            const float p0 = exp2f(x0 - mnew);
            const float p1 = exp2f(x1 - mnew);
            const float p2 = exp2f(x2 - mnew);
            const float p3 = exp2f(x3 - mnew);
            p[0][reg] = p0; p[1][reg] = p1; p[2][reg] = p2; p[3][reg] = p3;
            float ps = p0 + p1 + p2 + p3;
            #pragma unroll
            for (int d = 1; d < 16; d <<= 1) ps += __shfl_xor(ps, d);
            lrun[reg] = lrun[reg] * fs + ps;
            o[0][reg] *= fs; o[1][reg] *= fs; o[2][reg] *= fs; o[3][reg] *= fs;
        }

        // ---- P -> per-wave LDS (bf16, swizzled); same-wave DS is in-order ----
        #pragma unroll
        for (int t = 0; t < 4; ++t) {
            #pragma unroll
            for (int reg = 0; reg < 4; ++reg) {
                const unsigned int row  = (unsigned)(4 * g + reg);
                const unsigned int byte =
                    (row * 128u + (unsigned)(16 * t + m) * 2u) ^ ((row & 7u) << 4);
                *(unsigned short*)((char*)Pw + byte) = f2bf(p[t][reg]);
            }
        }

        // ---- PV: O[16q x 64d] += P[16 x 64] * V[64 x 64] ----
        #pragma unroll
        for (int kc = 0; kc < 2; ++kc) {
            const unsigned int arow = (unsigned)m;
            const unsigned int ab   =
                (arow * 128u + (unsigned)(32 * kc + 8 * g) * 2u) ^ ((arow & 7u) << 4);
            bf16x8 pa = *(const bf16x8*)((const char*)Pw + ab);
            #pragma unroll
            for (int dt = 0; dt < 4; ++dt) {
                const unsigned int d  = (unsigned)(16 * dt + m);
                const unsigned int vbyte =
                    (d * 128u + (unsigned)(32 * kc + 8 * g) * 2u) ^ ((d & 7u) << 4);
                bf16x8 vf = *(const bf16x8*)((const char*)Vb + vbyte);
                o[dt] = __builtin_amdgcn_mfma_f32_16x16x32_bf16(pa, vf, o[dt], 0, 0, 0);
            }
        }
    }

    // ---- epilogue: normalize by row-sum and store fp32 ----
    float inv[4];
    #pragma unroll
    for (int reg = 0; reg < 4; ++reg) inv[reg] = 1.0f / lrun[reg];
    #pragma unroll
    for (int reg = 0; reg < 4; ++reg) {
        const int qrow = qb + 16 * w + 4 * g + reg;
        float* dst = Op + (size_t)qrow * DH;
        #pragma unroll
        for (int dt = 0; dt < 4; ++dt) dst[16 * dt + m] = o[dt][reg] * inv[reg];
    }
}

extern "C" void kernel_launch(void* const* d_in, const int* in_sizes, int n_in,
                              void* d_out, int out_size, void* d_ws, size_t ws_size,
                              hipStream_t stream) {
    const float* Q = (const float*)d_in[0];
    const float* K = (const float*)d_in[1];
    const float* V = (const float*)d_in[2];
    float* O = (float*)d_out;
    dim3 grid(2 * 16 * NQT);   // B*H * (S/QBLK) = 1024
    dim3 block(256);
    fattn<<<grid, block, 0, stream>>>(Q, K, V, O);
}

// Round 4
// 246.421 us; speedup vs baseline: 1.2025x; 1.0950x over previous
//
#include <hip/hip_runtime.h>
#include <hip/hip_bf16.h>
#include <cstdint>
#include <cstddef>

#define SLEN 2048
#define DH   64
#define NQT  32          // SLEN / QBLK
#define QBLK 64
#define KVB  128
#define LOG2E 1.44269504088896340736f

typedef short  bf16x8 __attribute__((ext_vector_type(8)));
typedef float  f32x4  __attribute__((ext_vector_type(4)));

__device__ __forceinline__ unsigned short f2bf(float f) {
    __hip_bfloat16 h = __float2bfloat16(f);
    return *reinterpret_cast<unsigned short*>(&h);
}
__device__ __forceinline__ unsigned int pk2(float a, float b) {
    return (unsigned int)f2bf(a) | ((unsigned int)f2bf(b) << 16);
}

// Flash attention, causal, swapped-QK^T form: S^T = mfma(K_frag, Q_frag) so each
// lane holds a full q-row's scores in-register (row reduce = in-lane + 2
// butterflies over g instead of 8 over m). KVB=128 per iteration. One block =
// 64 q-rows of one (b,h), 4 waves x 16 rows. VGPR capped at 128 (4 waves/SIMD).
__global__ __launch_bounds__(256, 4) void fattn(const float* __restrict__ Qg,
                                                const float* __restrict__ Kg,
                                                const float* __restrict__ Vg,
                                                float* __restrict__ Og)
{
    // K: bf16 [k=128][d=64] rows 128B, swz byte^=((row&7)<<4)
    __shared__ __attribute__((aligned(16))) unsigned short Klds[KVB * DH];
    // V: bf16 TRANSPOSED [d=64][k=128] rows 256B, swz on d&7
    __shared__ __attribute__((aligned(16))) unsigned short Vlds[DH * KVB];
    // P per wave: bf16 [q=16][k=128] rows 256B, swz on m&7
    __shared__ __attribute__((aligned(16))) unsigned short Plds[4][16 * KVB];

    const int bid = blockIdx.x;
    const int hi4 = bid >> 8;          // 0..3
    const int lo8 = bid & 255;
    const int qx  = (int)((0x0F101F00u >> (8 * hi4)) & 31u);  // {0,31,16,15}
    const int qt  = (lo8 & 31) ^ qx;   // XOR balance: co-resident work sums const
    const int bh  = (hi4 << 3) | (lo8 >> 5);
    const int qb  = qt * QBLK;

    const float* Qp = Qg + (size_t)bh * SLEN * DH;
    const float* Kp = Kg + (size_t)bh * SLEN * DH;
    const float* Vp = Vg + (size_t)bh * SLEN * DH;
    float*       Op = Og + (size_t)bh * SLEN * DH;

    const int tid  = threadIdx.x;
    const int w    = tid >> 6;
    const int lane = tid & 63;
    const int g    = lane >> 4;
    const int m    = lane & 15;

    // ---- Q fragments (B operand): lane(g,m) = Q[qb+16w+m][32c+8g+j] ----
    bf16x8 qf[2];
    {
        const float sc = 0.125f * LOG2E;
        const int qrow = qb + 16 * w + m;
        #pragma unroll
        for (int c = 0; c < 2; ++c) {
            const float* src = Qp + (size_t)qrow * DH + 32 * c + 8 * g;
            float4 a = *reinterpret_cast<const float4*>(src);
            float4 b = *reinterpret_cast<const float4*>(src + 4);
            bf16x8 qv;
            qv[0]=(short)f2bf(a.x*sc); qv[1]=(short)f2bf(a.y*sc);
            qv[2]=(short)f2bf(a.z*sc); qv[3]=(short)f2bf(a.w*sc);
            qv[4]=(short)f2bf(b.x*sc); qv[5]=(short)f2bf(b.y*sc);
            qv[6]=(short)f2bf(b.z*sc); qv[7]=(short)f2bf(b.w*sc);
            qf[c] = qv;
        }
    }

    f32x4 o[4];
    #pragma unroll
    for (int dt = 0; dt < 4; ++dt) o[dt] = (f32x4){0.f, 0.f, 0.f, 0.f};
    float mrun = -1e30f, lrun = 0.f;   // per-lane stats for q-row = m

    const int klim = qb + QBLK;        // first invalid key for this block
    const int nt   = (qt + 2) >> 1;    // ceil((qt+1)*64 / 128)

    const int rk = tid & 127, hk = tid >> 7;   // K staging: row, d-half
    const int kp = tid & 63,  dq = tid >> 6;   // V staging: k-pair, d-quarter

    char* Pw = (char*)&Plds[w][0];
    const unsigned pswz = ((unsigned)(m & 7)) << 4;
    const int q = qb + 16 * w + m;

    for (int jt = 0; jt < nt; ++jt) {
        const int kvb    = jt * KVB;
        const int kwidth = min(KVB, klim - kvb);   // 64 (even-qt diag) or 128
        const bool last  = (jt == nt - 1);

        // ---- stage K: thread = (row rk, 32-float half hk) -> 4 b128 writes ----
        if (rk < kwidth) {
            const float4* s4 = reinterpret_cast<const float4*>(
                Kp + (size_t)(kvb + rk) * DH + 32 * hk);
            float4 x[8];
            #pragma unroll
            for (int i = 0; i < 8; ++i) x[i] = s4[i];
            const unsigned rswz = ((unsigned)(rk & 7)) << 4;
            #pragma unroll
            for (int c = 0; c < 4; ++c) {
                bf16x8 kb;
                kb[0]=(short)f2bf(x[2*c].x);   kb[1]=(short)f2bf(x[2*c].y);
                kb[2]=(short)f2bf(x[2*c].z);   kb[3]=(short)f2bf(x[2*c].w);
                kb[4]=(short)f2bf(x[2*c+1].x); kb[5]=(short)f2bf(x[2*c+1].y);
                kb[6]=(short)f2bf(x[2*c+1].z); kb[7]=(short)f2bf(x[2*c+1].w);
                const unsigned byte = (unsigned)(rk * 128 + 64 * hk + 16 * c);
                *(bf16x8*)((char*)Klds + (byte ^ rswz)) = kb;
            }
        }
        // ---- stage V transposed: thread = (rows 2kp,2kp+1, d-quarter dq);
        //      packs k-pairs -> 16 b32 writes ----
        if (2 * kp < kwidth) {
            const float* s0 = Vp + (size_t)(kvb + 2 * kp) * DH + 16 * dq;
            float av[16], bv[16];
            #pragma unroll
            for (int i = 0; i < 4; ++i) {
                float4 ta = *reinterpret_cast<const float4*>(s0 + 4 * i);
                float4 tb = *reinterpret_cast<const float4*>(s0 + DH + 4 * i);
                av[4*i]=ta.x; av[4*i+1]=ta.y; av[4*i+2]=ta.z; av[4*i+3]=ta.w;
                bv[4*i]=tb.x; bv[4*i+1]=tb.y; bv[4*i+2]=tb.z; bv[4*i+3]=tb.w;
            }
            #pragma unroll
            for (int j = 0; j < 16; ++j) {
                const int d = 16 * dq + j;
                const unsigned byte = (unsigned)(d * 256 + 4 * kp);
                *(unsigned*)((char*)Vlds + (byte ^ (((unsigned)(d & 7)) << 4))) =
                    pk2(av[j], bv[j]);
            }
        }
        __syncthreads();

        // ---- QK^T swapped: s[t] = S^T tile; lane(g,m) rows k=16t+4g+reg, col q=m ----
        f32x4 s[8];
        #pragma unroll
        for (int t = 0; t < 8; ++t) {
            if (16 * t < kwidth) {
                s[t] = (f32x4){0.f, 0.f, 0.f, 0.f};
                #pragma unroll
                for (int c = 0; c < 2; ++c) {
                    const unsigned row  = (unsigned)(16 * t + m);
                    const unsigned byte =
                        (row * 128u + (unsigned)(32 * c + 8 * g) * 2u) ^ ((row & 7u) << 4);
                    bf16x8 kf = *(const bf16x8*)((const char*)Klds + byte);
                    s[t] = __builtin_amdgcn_mfma_f32_16x16x32_bf16(kf, qf[c], s[t], 0, 0, 0);
                }
            }
        }

        // ---- softmax: row q=m fully lane-local; 2 butterflies over g ----
        float mx = -1e30f;
        #pragma unroll
        for (int t = 0; t < 8; ++t) {
            if (16 * t < kwidth) {
                #pragma unroll
                for (int r = 0; r < 4; ++r) {
                    float v = s[t][r];
                    if (last) {
                        const int kk = kvb + 16 * t + 4 * g + r;
                        v = (kk > q) ? -1e30f : v;
                    }
                    s[t][r] = v;
                    mx = fmaxf(mx, v);
                }
            }
        }
        mx = fmaxf(mx, __shfl_xor(mx, 16));
        mx = fmaxf(mx, __shfl_xor(mx, 32));
        const float mnew = fmaxf(mrun, mx);
        const float fs   = exp2f(mrun - mnew);
        mrun = mnew;

        float psum = 0.f;
        #pragma unroll
        for (int t = 0; t < 8; ++t) {
            if (16 * t < kwidth) {
                const float p0 = exp2f(s[t][0] - mnew);
                const float p1 = exp2f(s[t][1] - mnew);
                const float p2 = exp2f(s[t][2] - mnew);
                const float p3 = exp2f(s[t][3] - mnew);
                psum += (p0 + p1) + (p2 + p3);
                uint2 e;
                e.x = pk2(p0, p1);
                e.y = pk2(p2, p3);
                const unsigned byte = (unsigned)(m * 256 + 32 * t + 8 * g);
                *(uint2*)(Pw + (byte ^ pswz)) = e;   // same-wave DS is in-order
            }
        }
        psum += __shfl_xor(psum, 16);
        psum += __shfl_xor(psum, 32);
        lrun = lrun * fs + psum;

        // ---- rescale o (rows q-local = 4g+reg): broadcast fs from lane m'=4g+reg ----
        float fso[4];
        #pragma unroll
        for (int r = 0; r < 4; ++r)
            fso[r] = __shfl(fs, (lane & 48) | (4 * g + r));
        #pragma unroll
        for (int dt = 0; dt < 4; ++dt) {
            #pragma unroll
            for (int r = 0; r < 4; ++r) o[dt][r] *= fso[r];
        }

        // ---- PV: O[16q x 64d] += P[16 x kwidth] * V[kwidth x 64] ----
        const int kclim = kwidth >> 5;   // 2 or 4
        #pragma unroll
        for (int kc = 0; kc < 4; ++kc) {
            if (kc < kclim) {
                const unsigned ab = ((unsigned)(m * 256 + 64 * kc + 16 * g)) ^ pswz;
                bf16x8 pa = *(const bf16x8*)(Pw + ab);
                #pragma unroll
                for (int dt = 0; dt < 4; ++dt) {
                    const unsigned d  = (unsigned)(16 * dt + m);
                    const unsigned vb =
                        (d * 256u + (unsigned)(64 * kc + 16 * g)) ^ ((d & 7u) << 4);
                    bf16x8 vf = *(const bf16x8*)((const char*)Vlds + vb);
                    o[dt] = __builtin_amdgcn_mfma_f32_16x16x32_bf16(pa, vf, o[dt], 0, 0, 0);
                }
            }
        }
        __syncthreads();   // all waves done reading K/V before next stage
    }

    // ---- epilogue: broadcast 1/l to o-rows, store fp32 ----
    const float invl = 1.0f / lrun;
    float invo[4];
    #pragma unroll
    for (int r = 0; r < 4; ++r)
        invo[r] = __shfl(invl, (lane & 48) | (4 * g + r));
    #pragma unroll
    for (int r = 0; r < 4; ++r) {
        const int qrow = qb + 16 * w + 4 * g + r;
        float* dst = Op + (size_t)qrow * DH;
        #pragma unroll
        for (int dt = 0; dt < 4; ++dt) dst[16 * dt + m] = o[dt][r] * invo[r];
    }
}

extern "C" void kernel_launch(void* const* d_in, const int* in_sizes, int n_in,
                              void* d_out, int out_size, void* d_ws, size_t ws_size,
                              hipStream_t stream) {
    const float* Q = (const float*)d_in[0];
    const float* K = (const float*)d_in[1];
    const float* V = (const float*)d_in[2];
    float* O = (float*)d_out;
    dim3 grid(2 * 16 * NQT);   // B*H * (S/QBLK) = 1024
    dim3 block(256);
    fattn<<<grid, block, 0, stream>>>(Q, K, V, O);
}

// Round 5
// 194.104 us; speedup vs baseline: 1.5266x; 1.2695x over previous
//
#include <hip/hip_runtime.h>
#include <hip/hip_bf16.h>
#include <cstdint>
#include <cstddef>

#define SLEN 2048
#define DH   64
#define NQT  32          // SLEN / QBLK
#define QBLK 64
#define KVB  128
#define NHEADS 32        // B*H
#define LOG2E 1.44269504088896340736f

#define PRE_HEAD_BYTES (SLEN * DH * 2)          // 262144 per head (bf16)
#define TILE_BYTES     (KVB * DH * 2)           // 16384 per 128-row tile
#define VPRE_OFF       ((size_t)NHEADS * PRE_HEAD_BYTES)   // 8 MiB

typedef short  bf16x8 __attribute__((ext_vector_type(8)));
typedef float  f32x4  __attribute__((ext_vector_type(4)));

__device__ __forceinline__ unsigned short f2bf(float f) {
    __hip_bfloat16 h = __float2bfloat16(f);
    return *reinterpret_cast<unsigned short*>(&h);
}
__device__ __forceinline__ unsigned int pk2(float a, float b) {
    return (unsigned int)f2bf(a) | ((unsigned int)f2bf(b) << 16);
}

#define GLL(gp, lp)                                                            \
    __builtin_amdgcn_global_load_lds(                                          \
        (const __attribute__((address_space(1))) void*)(gp),                   \
        (__attribute__((address_space(3))) void*)(lp), 16, 0, 0)

// ---------------------------------------------------------------------------
// Prep: K -> bf16 [k][d] and V -> bf16 transposed [d][k], both stored in the
// PRE-SWIZZLED LDS image layout (byte ^ ((row&7)<<4) within each 16 KB tile),
// so the attention kernel can global_load_lds them linearly (m173 pattern).
// One thread per 16 B output chunk. Blocks 0..2047 = K, 2048..4095 = V.
// ---------------------------------------------------------------------------
__global__ __launch_bounds__(256) void prep(const float* __restrict__ Kg,
                                            const float* __restrict__ Vg,
                                            unsigned short* __restrict__ ws)
{
    const int bid = blockIdx.x;
    const int tid = threadIdx.x;
    if (bid < 2048) {
        const int cid = bid * 256 + tid;       // K chunk id
        const int h   = cid >> 14;             // 16384 chunks / head
        const int rem = cid & 16383;
        const int r   = rem >> 3;              // row 0..2047 (tile row = r&127)
        const int ccs = rem & 7;               // stored d-chunk
        const int d0  = 8 * (ccs ^ (r & 7));   // swizzle involution
        const float* src = Kg + ((size_t)h * SLEN + r) * DH + d0;
        float4 a = *reinterpret_cast<const float4*>(src);
        float4 b = *reinterpret_cast<const float4*>(src + 4);
        bf16x8 o;
        o[0]=(short)f2bf(a.x); o[1]=(short)f2bf(a.y);
        o[2]=(short)f2bf(a.z); o[3]=(short)f2bf(a.w);
        o[4]=(short)f2bf(b.x); o[5]=(short)f2bf(b.y);
        o[6]=(short)f2bf(b.z); o[7]=(short)f2bf(b.w);
        *(bf16x8*)((char*)ws + (size_t)cid * 16) = o;
    } else {
        const int cid  = (bid - 2048) * 256 + tid;   // V chunk id
        const int h    = cid >> 14;
        const int rem  = cid & 16383;
        const int t    = rem >> 10;            // 128-k tile
        const int rem2 = rem & 1023;           // 64 d-rows x 16 chunks
        const int d    = rem2 >> 4;
        const int ccs  = rem2 & 15;            // stored k-chunk
        const int k0   = 128 * t + 8 * (ccs ^ (d & 7));
        const float* src = Vg + ((size_t)h * SLEN + k0) * DH + d;
        bf16x8 o;
        #pragma unroll
        for (int j = 0; j < 8; ++j) o[j] = (short)f2bf(src[(size_t)j * DH]);
        *(bf16x8*)((char*)ws + VPRE_OFF + (size_t)cid * 16) = o;
    }
}

// ---------------------------------------------------------------------------
// Fast attention: K/V staged from pre-swizzled bf16 via global_load_lds,
// double-buffered, catalog T3-min 2-phase (STAGE next; compute cur; barrier).
// Swapped QK^T (lane owns a full q-row in-register). 80 KB LDS -> 2 blocks/CU.
// ---------------------------------------------------------------------------
__global__ __launch_bounds__(256, 2) void fattn_f(const float* __restrict__ Qg,
                                                  const unsigned short* __restrict__ KV,
                                                  float* __restrict__ Og)
{
    __shared__ __attribute__((aligned(16))) unsigned short Klds[2][KVB * DH];
    __shared__ __attribute__((aligned(16))) unsigned short Vlds[2][DH * KVB];
    __shared__ __attribute__((aligned(16))) unsigned short Plds[4][16 * KVB];

    const int bid = blockIdx.x;
    const int hi4 = bid >> 8;
    const int lo8 = bid & 255;
    const int qx  = (int)((0x0F101F00u >> (8 * hi4)) & 31u);  // {0,31,16,15}
    const int qt  = (lo8 & 31) ^ qx;   // XOR balance: co-resident work ~const
    const int bh  = (hi4 << 3) | (lo8 >> 5);
    const int qb  = qt * QBLK;

    const float* Qp   = Qg + (size_t)bh * SLEN * DH;
    const char*  Kpre = (const char*)KV + (size_t)bh * PRE_HEAD_BYTES;
    const char*  Vpre = (const char*)KV + VPRE_OFF + (size_t)bh * PRE_HEAD_BYTES;
    float*       Op   = Og + (size_t)bh * SLEN * DH;

    const int tid  = threadIdx.x;
    const int w    = tid >> 6;
    const int lane = tid & 63;
    const int g    = lane >> 4;
    const int m    = lane & 15;

    // ---- Q fragments (B operand): lane(g,m) = Q[qb+16w+m][32c+8g+j] ----
    bf16x8 qf[2];
    {
        const float sc = 0.125f * LOG2E;
        const int qrow = qb + 16 * w + m;
        #pragma unroll
        for (int c = 0; c < 2; ++c) {
            const float* src = Qp + (size_t)qrow * DH + 32 * c + 8 * g;
            float4 a = *reinterpret_cast<const float4*>(src);
            float4 b = *reinterpret_cast<const float4*>(src + 4);
            bf16x8 qv;
            qv[0]=(short)f2bf(a.x*sc); qv[1]=(short)f2bf(a.y*sc);
            qv[2]=(short)f2bf(a.z*sc); qv[3]=(short)f2bf(a.w*sc);
            qv[4]=(short)f2bf(b.x*sc); qv[5]=(short)f2bf(b.y*sc);
            qv[6]=(short)f2bf(b.z*sc); qv[7]=(short)f2bf(b.w*sc);
            qf[c] = qv;
        }
    }

    f32x4 o[4];
    #pragma unroll
    for (int dt = 0; dt < 4; ++dt) o[dt] = (f32x4){0.f, 0.f, 0.f, 0.f};
    float mrun = -1e30f, lrun = 0.f;   // per-lane stats for q-row = m

    const int klim = qb + QBLK;
    const int nt   = (qt + 2) >> 1;    // ceil((qt+1)*64 / 128)

    char* Pw = (char*)&Plds[w][0];
    const unsigned pswz = ((unsigned)(m & 7)) << 4;
    const int q = qb + 16 * w + m;

    // ---- staging: 8x global_load_lds dwordx4 (pre-swizzled src, linear dst)
    #define STAGE(jt_, buf_)                                                   \
        do {                                                                   \
            const char* gk_ = Kpre + (jt_) * TILE_BYTES + tid * 16;            \
            const char* gv_ = Vpre + (jt_) * TILE_BYTES + tid * 16;            \
            char* lk_ = (char*)&Klds[buf_][0] + tid * 16;                      \
            char* lv_ = (char*)&Vlds[buf_][0] + tid * 16;                      \
            GLL(gk_ + 0 * 4096, lk_ + 0 * 4096);                               \
            GLL(gk_ + 1 * 4096, lk_ + 1 * 4096);                               \
            GLL(gk_ + 2 * 4096, lk_ + 2 * 4096);                               \
            GLL(gk_ + 3 * 4096, lk_ + 3 * 4096);                               \
            GLL(gv_ + 0 * 4096, lv_ + 0 * 4096);                               \
            GLL(gv_ + 1 * 4096, lv_ + 1 * 4096);                               \
            GLL(gv_ + 2 * 4096, lv_ + 2 * 4096);                               \
            GLL(gv_ + 3 * 4096, lv_ + 3 * 4096);                               \
        } while (0)

    int buf = 0;
    STAGE(0, 0);
    __syncthreads();   // compiler drains vmcnt(0) before s_barrier: buf0 ready

    for (int jt = 0; jt < nt; ++jt) {
        const int kvb    = jt * KVB;
        const int kwidth = min(KVB, klim - kvb);   // 64 (even-qt tail) or 128
        const bool last  = (jt == nt - 1);

        if (jt + 1 < nt) STAGE(jt + 1, buf ^ 1);   // loads fly under compute

        const char* Kb = (const char*)&Klds[buf][0];
        const char* Vb = (const char*)&Vlds[buf][0];

        // ---- QK^T swapped: s[t] rows k=16t+4g+r, col q=m ----
        f32x4 s[8];
        #pragma unroll
        for (int t = 0; t < 8; ++t) {
            if (16 * t < kwidth) {
                s[t] = (f32x4){0.f, 0.f, 0.f, 0.f};
                #pragma unroll
                for (int c = 0; c < 2; ++c) {
                    const unsigned row  = (unsigned)(16 * t + m);
                    const unsigned byte =
                        (row * 128u + (unsigned)(32 * c + 8 * g) * 2u) ^ ((row & 7u) << 4);
                    bf16x8 kf = *(const bf16x8*)(Kb + byte);
                    s[t] = __builtin_amdgcn_mfma_f32_16x16x32_bf16(kf, qf[c], s[t], 0, 0, 0);
                }
            }
        }

        // ---- softmax: row q=m lane-local; 2 butterflies over g ----
        float mx = -1e30f;
        #pragma unroll
        for (int t = 0; t < 8; ++t) {
            if (16 * t < kwidth) {
                #pragma unroll
                for (int r = 0; r < 4; ++r) {
                    float v = s[t][r];
                    if (last) {
                        const int kk = kvb + 16 * t + 4 * g + r;
                        v = (kk > q) ? -1e30f : v;
                    }
                    s[t][r] = v;
                    mx = fmaxf(mx, v);
                }
            }
        }
        mx = fmaxf(mx, __shfl_xor(mx, 16));
        mx = fmaxf(mx, __shfl_xor(mx, 32));
        const float mnew = fmaxf(mrun, mx);
        const float fs   = exp2f(mrun - mnew);
        mrun = mnew;

        float psum = 0.f;
        #pragma unroll
        for (int t = 0; t < 8; ++t) {
            if (16 * t < kwidth) {
                const float p0 = exp2f(s[t][0] - mnew);
                const float p1 = exp2f(s[t][1] - mnew);
                const float p2 = exp2f(s[t][2] - mnew);
                const float p3 = exp2f(s[t][3] - mnew);
                psum += (p0 + p1) + (p2 + p3);
                uint2 e;
                e.x = pk2(p0, p1);
                e.y = pk2(p2, p3);
                const unsigned byte = (unsigned)(m * 256 + 32 * t + 8 * g);
                *(uint2*)(Pw + (byte ^ pswz)) = e;   // same-wave DS in-order
            }
        }
        psum += __shfl_xor(psum, 16);
        psum += __shfl_xor(psum, 32);
        lrun = lrun * fs + psum;

        // ---- rescale o rows (q-local = 4g+r): fs from lane m'=4g+r ----
        float fso[4];
        #pragma unroll
        for (int r = 0; r < 4; ++r)
            fso[r] = __shfl(fs, (lane & 48) | (4 * g + r));
        #pragma unroll
        for (int dt = 0; dt < 4; ++dt) {
            #pragma unroll
            for (int r = 0; r < 4; ++r) o[dt][r] *= fso[r];
        }

        // ---- PV: O[16q x 64d] += P[16 x kwidth] * V[kwidth x 64] ----
        const int kclim = kwidth >> 5;   // 2 or 4
        #pragma unroll
        for (int kc = 0; kc < 4; ++kc) {
            if (kc < kclim) {
                const unsigned ab = ((unsigned)(m * 256 + 64 * kc + 16 * g)) ^ pswz;
                bf16x8 pa = *(const bf16x8*)(Pw + ab);
                #pragma unroll
                for (int dt = 0; dt < 4; ++dt) {
                    const unsigned d  = (unsigned)(16 * dt + m);
                    const unsigned vb =
                        (d * 256u + (unsigned)(64 * kc + 16 * g)) ^ ((d & 7u) << 4);
                    bf16x8 vf = *(const bf16x8*)(Vb + vb);
                    o[dt] = __builtin_amdgcn_mfma_f32_16x16x32_bf16(pa, vf, o[dt], 0, 0, 0);
                }
            }
        }

        __syncthreads();   // readers of buf done + buf^1 loads landed
        buf ^= 1;
    }
    #undef STAGE

    // ---- epilogue ----
    const float invl = 1.0f / lrun;
    float invo[4];
    #pragma unroll
    for (int r = 0; r < 4; ++r)
        invo[r] = __shfl(invl, (lane & 48) | (4 * g + r));
    #pragma unroll
    for (int r = 0; r < 4; ++r) {
        const int qrow = qb + 16 * w + 4 * g + r;
        float* dst = Op + (size_t)qrow * DH;
        #pragma unroll
        for (int dt = 0; dt < 4; ++dt) dst[16 * dt + m] = o[dt][r] * invo[r];
    }
}

// ---------------------------------------------------------------------------
// Fallback (validated round-4 kernel) if ws_size is too small for KV prep.
// ---------------------------------------------------------------------------
__global__ __launch_bounds__(256, 4) void fattn_s(const float* __restrict__ Qg,
                                                  const float* __restrict__ Kg,
                                                  const float* __restrict__ Vg,
                                                  float* __restrict__ Og)
{
    __shared__ __attribute__((aligned(16))) unsigned short Klds[KVB * DH];
    __shared__ __attribute__((aligned(16))) unsigned short Vlds[DH * KVB];
    __shared__ __attribute__((aligned(16))) unsigned short Plds[4][16 * KVB];

    const int bid = blockIdx.x;
    const int hi4 = bid >> 8;
    const int lo8 = bid & 255;
    const int qx  = (int)((0x0F101F00u >> (8 * hi4)) & 31u);
    const int qt  = (lo8 & 31) ^ qx;
    const int bh  = (hi4 << 3) | (lo8 >> 5);
    const int qb  = qt * QBLK;

    const float* Qp = Qg + (size_t)bh * SLEN * DH;
    const float* Kp = Kg + (size_t)bh * SLEN * DH;
    const float* Vp = Vg + (size_t)bh * SLEN * DH;
    float*       Op = Og + (size_t)bh * SLEN * DH;

    const int tid  = threadIdx.x;
    const int w    = tid >> 6;
    const int lane = tid & 63;
    const int g    = lane >> 4;
    const int m    = lane & 15;

    bf16x8 qf[2];
    {
        const float sc = 0.125f * LOG2E;
        const int qrow = qb + 16 * w + m;
        #pragma unroll
        for (int c = 0; c < 2; ++c) {
            const float* src = Qp + (size_t)qrow * DH + 32 * c + 8 * g;
            float4 a = *reinterpret_cast<const float4*>(src);
            float4 b = *reinterpret_cast<const float4*>(src + 4);
            bf16x8 qv;
            qv[0]=(short)f2bf(a.x*sc); qv[1]=(short)f2bf(a.y*sc);
            qv[2]=(short)f2bf(a.z*sc); qv[3]=(short)f2bf(a.w*sc);
            qv[4]=(short)f2bf(b.x*sc); qv[5]=(short)f2bf(b.y*sc);
            qv[6]=(short)f2bf(b.z*sc); qv[7]=(short)f2bf(b.w*sc);
            qf[c] = qv;
        }
    }

    f32x4 o[4];
    #pragma unroll
    for (int dt = 0; dt < 4; ++dt) o[dt] = (f32x4){0.f, 0.f, 0.f, 0.f};
    float mrun = -1e30f, lrun = 0.f;

    const int klim = qb + QBLK;
    const int nt   = (qt + 2) >> 1;

    const int rk = tid & 127, hk = tid >> 7;
    const int kp = tid & 63,  dq = tid >> 6;

    char* Pw = (char*)&Plds[w][0];
    const unsigned pswz = ((unsigned)(m & 7)) << 4;
    const int q = qb + 16 * w + m;

    for (int jt = 0; jt < nt; ++jt) {
        const int kvb    = jt * KVB;
        const int kwidth = min(KVB, klim - kvb);
        const bool last  = (jt == nt - 1);

        if (rk < kwidth) {
            const float4* s4 = reinterpret_cast<const float4*>(
                Kp + (size_t)(kvb + rk) * DH + 32 * hk);
            float4 x[8];
            #pragma unroll
            for (int i = 0; i < 8; ++i) x[i] = s4[i];
            const unsigned rswz = ((unsigned)(rk & 7)) << 4;
            #pragma unroll
            for (int c = 0; c < 4; ++c) {
                bf16x8 kb;
                kb[0]=(short)f2bf(x[2*c].x);   kb[1]=(short)f2bf(x[2*c].y);
                kb[2]=(short)f2bf(x[2*c].z);   kb[3]=(short)f2bf(x[2*c].w);
                kb[4]=(short)f2bf(x[2*c+1].x); kb[5]=(short)f2bf(x[2*c+1].y);
                kb[6]=(short)f2bf(x[2*c+1].z); kb[7]=(short)f2bf(x[2*c+1].w);
                const unsigned byte = (unsigned)(rk * 128 + 64 * hk + 16 * c);
                *(bf16x8*)((char*)Klds + (byte ^ rswz)) = kb;
            }
        }
        if (2 * kp < kwidth) {
            const float* s0 = Vp + (size_t)(kvb + 2 * kp) * DH + 16 * dq;
            float av[16], bv[16];
            #pragma unroll
            for (int i = 0; i < 4; ++i) {
                float4 ta = *reinterpret_cast<const float4*>(s0 + 4 * i);
                float4 tb = *reinterpret_cast<const float4*>(s0 + DH + 4 * i);
                av[4*i]=ta.x; av[4*i+1]=ta.y; av[4*i+2]=ta.z; av[4*i+3]=ta.w;
                bv[4*i]=tb.x; bv[4*i+1]=tb.y; bv[4*i+2]=tb.z; bv[4*i+3]=tb.w;
            }
            #pragma unroll
            for (int j = 0; j < 16; ++j) {
                const int d = 16 * dq + j;
                const unsigned byte = (unsigned)(d * 256 + 4 * kp);
                *(unsigned*)((char*)Vlds + (byte ^ (((unsigned)(d & 7)) << 4))) =
                    pk2(av[j], bv[j]);
            }
        }
        __syncthreads();

        f32x4 s[8];
        #pragma unroll
        for (int t = 0; t < 8; ++t) {
            if (16 * t < kwidth) {
                s[t] = (f32x4){0.f, 0.f, 0.f, 0.f};
                #pragma unroll
                for (int c = 0; c < 2; ++c) {
                    const unsigned row  = (unsigned)(16 * t + m);
                    const unsigned byte =
                        (row * 128u + (unsigned)(32 * c + 8 * g) * 2u) ^ ((row & 7u) << 4);
                    bf16x8 kf = *(const bf16x8*)((const char*)Klds + byte);
                    s[t] = __builtin_amdgcn_mfma_f32_16x16x32_bf16(kf, qf[c], s[t], 0, 0, 0);
                }
            }
        }

        float mx = -1e30f;
        #pragma unroll
        for (int t = 0; t < 8; ++t) {
            if (16 * t < kwidth) {
                #pragma unroll
                for (int r = 0; r < 4; ++r) {
                    float v = s[t][r];
                    if (last) {
                        const int kk = kvb + 16 * t + 4 * g + r;
                        v = (kk > q) ? -1e30f : v;
                    }
                    s[t][r] = v;
                    mx = fmaxf(mx, v);
                }
            }
        }
        mx = fmaxf(mx, __shfl_xor(mx, 16));
        mx = fmaxf(mx, __shfl_xor(mx, 32));
        const float mnew = fmaxf(mrun, mx);
        const float fs   = exp2f(mrun - mnew);
        mrun = mnew;

        float psum = 0.f;
        #pragma unroll
        for (int t = 0; t < 8; ++t) {
            if (16 * t < kwidth) {
                const float p0 = exp2f(s[t][0] - mnew);
                const float p1 = exp2f(s[t][1] - mnew);
                const float p2 = exp2f(s[t][2] - mnew);
                const float p3 = exp2f(s[t][3] - mnew);
                psum += (p0 + p1) + (p2 + p3);
                uint2 e;
                e.x = pk2(p0, p1);
                e.y = pk2(p2, p3);
                const unsigned byte = (unsigned)(m * 256 + 32 * t + 8 * g);
                *(uint2*)(Pw + (byte ^ pswz)) = e;
            }
        }
        psum += __shfl_xor(psum, 16);
        psum += __shfl_xor(psum, 32);
        lrun = lrun * fs + psum;

        float fso[4];
        #pragma unroll
        for (int r = 0; r < 4; ++r)
            fso[r] = __shfl(fs, (lane & 48) | (4 * g + r));
        #pragma unroll
        for (int dt = 0; dt < 4; ++dt) {
            #pragma unroll
            for (int r = 0; r < 4; ++r) o[dt][r] *= fso[r];
        }

        const int kclim = kwidth >> 5;
        #pragma unroll
        for (int kc = 0; kc < 4; ++kc) {
            if (kc < kclim) {
                const unsigned ab = ((unsigned)(m * 256 + 64 * kc + 16 * g)) ^ pswz;
                bf16x8 pa = *(const bf16x8*)(Pw + ab);
                #pragma unroll
                for (int dt = 0; dt < 4; ++dt) {
                    const unsigned d  = (unsigned)(16 * dt + m);
                    const unsigned vb =
                        (d * 256u + (unsigned)(64 * kc + 16 * g)) ^ ((d & 7u) << 4);
                    bf16x8 vf = *(const bf16x8*)((const char*)Vlds + vb);
                    o[dt] = __builtin_amdgcn_mfma_f32_16x16x32_bf16(pa, vf, o[dt], 0, 0, 0);
                }
            }
        }
        __syncthreads();
    }

    const float invl = 1.0f / lrun;
    float invo[4];
    #pragma unroll
    for (int r = 0; r < 4; ++r)
        invo[r] = __shfl(invl, (lane & 48) | (4 * g + r));
    #pragma unroll
    for (int r = 0; r < 4; ++r) {
        const int qrow = qb + 16 * w + 4 * g + r;
        float* dst = Op + (size_t)qrow * DH;
        #pragma unroll
        for (int dt = 0; dt < 4; ++dt) dst[16 * dt + m] = o[dt][r] * invo[r];
    }
}

extern "C" void kernel_launch(void* const* d_in, const int* in_sizes, int n_in,
                              void* d_out, int out_size, void* d_ws, size_t ws_size,
                              hipStream_t stream) {
    const float* Q = (const float*)d_in[0];
    const float* K = (const float*)d_in[1];
    const float* V = (const float*)d_in[2];
    float* O = (float*)d_out;
    if (ws_size >= 2 * VPRE_OFF) {
        unsigned short* ws = (unsigned short*)d_ws;
        prep<<<dim3(4096), dim3(256), 0, stream>>>(K, V, ws);
        fattn_f<<<dim3(1024), dim3(256), 0, stream>>>(Q, ws, O);
    } else {
        fattn_s<<<dim3(1024), dim3(256), 0, stream>>>(Q, K, V, O);
    }
}

// Round 6
// 158.208 us; speedup vs baseline: 1.8729x; 1.2269x over previous
//
#include <hip/hip_runtime.h>
#include <hip/hip_bf16.h>
#include <cstdint>
#include <cstddef>

#define SLEN 2048
#define DH   64
#define NQT  32          // SLEN / QBLK
#define QBLK 64
#define KVB  64          // fast-path kv tile
#define NHEADS 32        // B*H
#define LOG2E 1.44269504088896340736f

#define PRE_HEAD_BYTES (SLEN * DH * 2)          // 262144 per head (bf16)
#define TILE_BYTES     (KVB * DH * 2)           // 8192 per 64-row tile
#define VPRE_OFF       ((size_t)NHEADS * PRE_HEAD_BYTES)   // 8 MiB

typedef short  bf16x8 __attribute__((ext_vector_type(8)));
typedef float  f32x4  __attribute__((ext_vector_type(4)));

__device__ __forceinline__ unsigned short f2bf(float f) {
    __hip_bfloat16 h = __float2bfloat16(f);
    return *reinterpret_cast<unsigned short*>(&h);
}
__device__ __forceinline__ unsigned int pk2(float a, float b) {
    return (unsigned int)f2bf(a) | ((unsigned int)f2bf(b) << 16);
}

#define GLL(gp, lp)                                                            \
    __builtin_amdgcn_global_load_lds(                                          \
        (const __attribute__((address_space(1))) void*)(gp),                   \
        (__attribute__((address_space(3))) void*)(lp), 16, 0, 0)

// ---------------------------------------------------------------------------
// Prep: K -> bf16 [k][d] rows (swizzled LDS image), V -> bf16 transposed
// [d][k] per 64-k tile (swizzled image). K path: elementwise, coalesced both
// sides (blocks 0..2047). V path: per-tile LDS transpose, coalesced fp32
// reads + coalesced bf16 writes (blocks 2048..3071).
// ---------------------------------------------------------------------------
__global__ __launch_bounds__(256) void prep(const float* __restrict__ Kg,
                                            const float* __restrict__ Vg,
                                            unsigned short* __restrict__ ws)
{
    const int bid = blockIdx.x;
    const int tid = threadIdx.x;
    if (bid < 2048) {
        // ---- K: one 16B bf16 chunk per thread ----
        const int cid = bid * 256 + tid;       // chunk id
        const int h   = cid >> 14;             // 16384 chunks / head
        const int rem = cid & 16383;
        const int r   = rem >> 3;              // row 0..2047
        const int ccs = rem & 7;               // stored d-chunk
        const int d0  = 8 * (ccs ^ (r & 7));   // swizzle involution
        const float* src = Kg + ((size_t)h * SLEN + r) * DH + d0;
        float4 a = *reinterpret_cast<const float4*>(src);
        float4 b = *reinterpret_cast<const float4*>(src + 4);
        bf16x8 o;
        o[0]=(short)f2bf(a.x); o[1]=(short)f2bf(a.y);
        o[2]=(short)f2bf(a.z); o[3]=(short)f2bf(a.w);
        o[4]=(short)f2bf(b.x); o[5]=(short)f2bf(b.y);
        o[6]=(short)f2bf(b.z); o[7]=(short)f2bf(b.w);
        *(bf16x8*)((char*)ws + (size_t)cid * 16) = o;
    } else {
        // ---- V: one 64k x 64d tile per block, transpose via LDS ----
        __shared__ __attribute__((aligned(16))) unsigned short Vt[KVB * DH];
        const int vb = bid - 2048;
        const int h  = vb >> 5;                // head
        const int t  = vb & 31;                // 64-k tile
        const int do8 = tid & 7;               // d-octet: d = 8*do8 + j
        const int kp  = tid >> 3;              // k-pair: rows 2kp, 2kp+1
        const float* s0 = Vg + ((size_t)h * SLEN + (size_t)t * KVB + 2 * kp) * DH + 8 * do8;
        float4 a0 = *reinterpret_cast<const float4*>(s0);
        float4 a1 = *reinterpret_cast<const float4*>(s0 + 4);
        float4 b0 = *reinterpret_cast<const float4*>(s0 + DH);
        float4 b1 = *reinterpret_cast<const float4*>(s0 + DH + 4);
        float av[8] = {a0.x,a0.y,a0.z,a0.w,a1.x,a1.y,a1.z,a1.w};
        float bv[8] = {b0.x,b0.y,b0.z,b0.w,b1.x,b1.y,b1.z,b1.w};
        #pragma unroll
        for (int j = 0; j < 8; ++j) {
            const int d = 8 * do8 + j;
            const unsigned byte =
                ((unsigned)(d * 128 + 4 * kp)) ^ (((unsigned)(d & 7)) << 4);
            *(unsigned*)((char*)Vt + byte) = pk2(av[j], bv[j]);
        }
        __syncthreads();
        // linear coalesced copy-out: 32 B per thread
        char* gdst = (char*)ws + VPRE_OFF + (size_t)h * PRE_HEAD_BYTES
                   + (size_t)t * TILE_BYTES + (size_t)tid * 32;
        const char* lsrc = (const char*)Vt + tid * 32;
        *(bf16x8*)(gdst)      = *(const bf16x8*)(lsrc);
        *(bf16x8*)(gdst + 16) = *(const bf16x8*)(lsrc + 16);
    }
}

// ---------------------------------------------------------------------------
// Fast attention: K/V staged from pre-swizzled bf16 via global_load_lds,
// KVB=64 double-buffered -> 40 KB LDS -> 4 blocks/CU (4 waves/SIMD TLP).
// Swapped QK^T: lane owns a full q-row's scores in-register.
// ---------------------------------------------------------------------------
__global__ __launch_bounds__(256, 4) void fattn_f(const float* __restrict__ Qg,
                                                  const unsigned short* __restrict__ KV,
                                                  float* __restrict__ Og)
{
    __shared__ __attribute__((aligned(16))) unsigned short Klds[2][KVB * DH];
    __shared__ __attribute__((aligned(16))) unsigned short Vlds[2][DH * KVB];
    __shared__ __attribute__((aligned(16))) unsigned short Plds[4][16 * KVB];

    const int bid = blockIdx.x;
    const int hi4 = bid >> 8;
    const int lo8 = bid & 255;
    const int qx  = (int)((0x0F101F00u >> (8 * hi4)) & 31u);  // {0,31,16,15}
    const int qt  = (lo8 & 31) ^ qx;   // XOR balance: co-resident work ~const
    const int bh  = (hi4 << 3) | (lo8 >> 5);
    const int qb  = qt * QBLK;

    const float* Qp   = Qg + (size_t)bh * SLEN * DH;
    const char*  Kpre = (const char*)KV + (size_t)bh * PRE_HEAD_BYTES;
    const char*  Vpre = (const char*)KV + VPRE_OFF + (size_t)bh * PRE_HEAD_BYTES;
    float*       Op   = Og + (size_t)bh * SLEN * DH;

    const int tid  = threadIdx.x;
    const int w    = tid >> 6;
    const int lane = tid & 63;
    const int g    = lane >> 4;
    const int m    = lane & 15;

    // ---- Q fragments (B operand): lane(g,m) = Q[qb+16w+m][32c+8g+j] ----
    bf16x8 qf[2];
    {
        const float sc = 0.125f * LOG2E;
        const int qrow = qb + 16 * w + m;
        #pragma unroll
        for (int c = 0; c < 2; ++c) {
            const float* src = Qp + (size_t)qrow * DH + 32 * c + 8 * g;
            float4 a = *reinterpret_cast<const float4*>(src);
            float4 b = *reinterpret_cast<const float4*>(src + 4);
            bf16x8 qv;
            qv[0]=(short)f2bf(a.x*sc); qv[1]=(short)f2bf(a.y*sc);
            qv[2]=(short)f2bf(a.z*sc); qv[3]=(short)f2bf(a.w*sc);
            qv[4]=(short)f2bf(b.x*sc); qv[5]=(short)f2bf(b.y*sc);
            qv[6]=(short)f2bf(b.z*sc); qv[7]=(short)f2bf(b.w*sc);
            qf[c] = qv;
        }
    }

    f32x4 o[4];
    #pragma unroll
    for (int dt = 0; dt < 4; ++dt) o[dt] = (f32x4){0.f, 0.f, 0.f, 0.f};
    float mrun = -1e30f, lrun = 0.f;   // per-lane stats for q-row = m

    const int nt = qt + 1;             // 64-wide tiles

    char* Pw = (char*)&Plds[w][0];
    const unsigned pswz = ((unsigned)(m & 7)) << 4;
    const int q = qb + 16 * w + m;

    // ---- staging: 4x global_load_lds dwordx4 (pre-swizzled src, linear dst)
    #define STAGE(jt_, buf_)                                                   \
        do {                                                                   \
            const char* gk_ = Kpre + (size_t)(jt_) * TILE_BYTES + tid * 16;    \
            const char* gv_ = Vpre + (size_t)(jt_) * TILE_BYTES + tid * 16;    \
            char* lk_ = (char*)&Klds[buf_][0] + tid * 16;                      \
            char* lv_ = (char*)&Vlds[buf_][0] + tid * 16;                      \
            GLL(gk_,        lk_);                                              \
            GLL(gk_ + 4096, lk_ + 4096);                                       \
            GLL(gv_,        lv_);                                              \
            GLL(gv_ + 4096, lv_ + 4096);                                       \
        } while (0)

    int buf = 0;
    STAGE(0, 0);
    __syncthreads();   // vmcnt(0) drained before barrier: buf0 ready

    for (int jt = 0; jt < nt; ++jt) {
        const int kvb   = jt * KVB;
        const bool last = (jt == nt - 1);

        if (jt + 1 < nt) STAGE(jt + 1, buf ^ 1);   // loads fly under compute

        const char* Kb = (const char*)&Klds[buf][0];
        const char* Vb = (const char*)&Vlds[buf][0];

        // ---- QK^T swapped: s[t] rows k=16t+4g+r, col q=m ----
        f32x4 s[4];
        #pragma unroll
        for (int t = 0; t < 4; ++t) {
            s[t] = (f32x4){0.f, 0.f, 0.f, 0.f};
            #pragma unroll
            for (int c = 0; c < 2; ++c) {
                const unsigned row  = (unsigned)(16 * t + m);
                const unsigned byte =
                    (row * 128u + (unsigned)(32 * c + 8 * g) * 2u) ^ ((row & 7u) << 4);
                bf16x8 kf = *(const bf16x8*)(Kb + byte);
                s[t] = __builtin_amdgcn_mfma_f32_16x16x32_bf16(kf, qf[c], s[t], 0, 0, 0);
            }
        }

        // ---- softmax: row q=m lane-local; 2 butterflies over g ----
        float mx = -1e30f;
        #pragma unroll
        for (int t = 0; t < 4; ++t) {
            #pragma unroll
            for (int r = 0; r < 4; ++r) {
                float v = s[t][r];
                if (last) {
                    const int kk = kvb + 16 * t + 4 * g + r;
                    v = (kk > q) ? -1e30f : v;
                }
                s[t][r] = v;
                mx = fmaxf(mx, v);
            }
        }
        mx = fmaxf(mx, __shfl_xor(mx, 16));
        mx = fmaxf(mx, __shfl_xor(mx, 32));
        const float mnew = fmaxf(mrun, mx);
        const float fs   = exp2f(mrun - mnew);
        mrun = mnew;

        float psum = 0.f;
        #pragma unroll
        for (int t = 0; t < 4; ++t) {
            const float p0 = exp2f(s[t][0] - mnew);
            const float p1 = exp2f(s[t][1] - mnew);
            const float p2 = exp2f(s[t][2] - mnew);
            const float p3 = exp2f(s[t][3] - mnew);
            psum += (p0 + p1) + (p2 + p3);
            uint2 e;
            e.x = pk2(p0, p1);
            e.y = pk2(p2, p3);
            const unsigned byte = (unsigned)(m * 128 + 32 * t + 8 * g);
            *(uint2*)(Pw + (byte ^ pswz)) = e;   // same-wave DS in-order
        }
        psum += __shfl_xor(psum, 16);
        psum += __shfl_xor(psum, 32);
        lrun = lrun * fs + psum;

        // ---- rescale o rows (q-local = 4g+r): fs from lane m'=4g+r ----
        float fso[4];
        #pragma unroll
        for (int r = 0; r < 4; ++r)
            fso[r] = __shfl(fs, (lane & 48) | (4 * g + r));
        #pragma unroll
        for (int dt = 0; dt < 4; ++dt) {
            #pragma unroll
            for (int r = 0; r < 4; ++r) o[dt][r] *= fso[r];
        }

        // ---- PV: O[16q x 64d] += P[16 x 64] * V[64 x 64] ----
        #pragma unroll
        for (int kc = 0; kc < 2; ++kc) {
            const unsigned ab = ((unsigned)(m * 128 + 64 * kc + 16 * g)) ^ pswz;
            bf16x8 pa = *(const bf16x8*)(Pw + ab);
            #pragma unroll
            for (int dt = 0; dt < 4; ++dt) {
                const unsigned d  = (unsigned)(16 * dt + m);
                const unsigned vby =
                    (d * 128u + (unsigned)(64 * kc + 16 * g)) ^ ((d & 7u) << 4);
                bf16x8 vf = *(const bf16x8*)(Vb + vby);
                o[dt] = __builtin_amdgcn_mfma_f32_16x16x32_bf16(pa, vf, o[dt], 0, 0, 0);
            }
        }

        __syncthreads();   // readers of buf done + buf^1 loads landed
        buf ^= 1;
    }
    #undef STAGE

    // ---- epilogue ----
    const float invl = 1.0f / lrun;
    float invo[4];
    #pragma unroll
    for (int r = 0; r < 4; ++r)
        invo[r] = __shfl(invl, (lane & 48) | (4 * g + r));
    #pragma unroll
    for (int r = 0; r < 4; ++r) {
        const int qrow = qb + 16 * w + 4 * g + r;
        float* dst = Op + (size_t)qrow * DH;
        #pragma unroll
        for (int dt = 0; dt < 4; ++dt) dst[16 * dt + m] = o[dt][r] * invo[r];
    }
}

// ---------------------------------------------------------------------------
// Fallback (validated round-4 kernel, KVB=128 inline) if ws too small.
// ---------------------------------------------------------------------------
__global__ __launch_bounds__(256, 4) void fattn_s(const float* __restrict__ Qg,
                                                  const float* __restrict__ Kg,
                                                  const float* __restrict__ Vg,
                                                  float* __restrict__ Og)
{
    __shared__ __attribute__((aligned(16))) unsigned short Klds[128 * DH];
    __shared__ __attribute__((aligned(16))) unsigned short Vlds[DH * 128];
    __shared__ __attribute__((aligned(16))) unsigned short Plds[4][16 * 128];

    const int bid = blockIdx.x;
    const int hi4 = bid >> 8;
    const int lo8 = bid & 255;
    const int qx  = (int)((0x0F101F00u >> (8 * hi4)) & 31u);
    const int qt  = (lo8 & 31) ^ qx;
    const int bh  = (hi4 << 3) | (lo8 >> 5);
    const int qb  = qt * QBLK;

    const float* Qp = Qg + (size_t)bh * SLEN * DH;
    const float* Kp = Kg + (size_t)bh * SLEN * DH;
    const float* Vp = Vg + (size_t)bh * SLEN * DH;
    float*       Op = Og + (size_t)bh * SLEN * DH;

    const int tid  = threadIdx.x;
    const int w    = tid >> 6;
    const int lane = tid & 63;
    const int g    = lane >> 4;
    const int m    = lane & 15;

    bf16x8 qf[2];
    {
        const float sc = 0.125f * LOG2E;
        const int qrow = qb + 16 * w + m;
        #pragma unroll
        for (int c = 0; c < 2; ++c) {
            const float* src = Qp + (size_t)qrow * DH + 32 * c + 8 * g;
            float4 a = *reinterpret_cast<const float4*>(src);
            float4 b = *reinterpret_cast<const float4*>(src + 4);
            bf16x8 qv;
            qv[0]=(short)f2bf(a.x*sc); qv[1]=(short)f2bf(a.y*sc);
            qv[2]=(short)f2bf(a.z*sc); qv[3]=(short)f2bf(a.w*sc);
            qv[4]=(short)f2bf(b.x*sc); qv[5]=(short)f2bf(b.y*sc);
            qv[6]=(short)f2bf(b.z*sc); qv[7]=(short)f2bf(b.w*sc);
            qf[c] = qv;
        }
    }

    f32x4 o[4];
    #pragma unroll
    for (int dt = 0; dt < 4; ++dt) o[dt] = (f32x4){0.f, 0.f, 0.f, 0.f};
    float mrun = -1e30f, lrun = 0.f;

    const int klim = qb + QBLK;
    const int nt   = (qt + 2) >> 1;

    const int rk = tid & 127, hk = tid >> 7;
    const int kp = tid & 63,  dq = tid >> 6;

    char* Pw = (char*)&Plds[w][0];
    const unsigned pswz = ((unsigned)(m & 7)) << 4;
    const int q = qb + 16 * w + m;

    for (int jt = 0; jt < nt; ++jt) {
        const int kvb    = jt * 128;
        const int kwidth = min(128, klim - kvb);
        const bool last  = (jt == nt - 1);

        if (rk < kwidth) {
            const float4* s4 = reinterpret_cast<const float4*>(
                Kp + (size_t)(kvb + rk) * DH + 32 * hk);
            float4 x[8];
            #pragma unroll
            for (int i = 0; i < 8; ++i) x[i] = s4[i];
            const unsigned rswz = ((unsigned)(rk & 7)) << 4;
            #pragma unroll
            for (int c = 0; c < 4; ++c) {
                bf16x8 kb;
                kb[0]=(short)f2bf(x[2*c].x);   kb[1]=(short)f2bf(x[2*c].y);
                kb[2]=(short)f2bf(x[2*c].z);   kb[3]=(short)f2bf(x[2*c].w);
                kb[4]=(short)f2bf(x[2*c+1].x); kb[5]=(short)f2bf(x[2*c+1].y);
                kb[6]=(short)f2bf(x[2*c+1].z); kb[7]=(short)f2bf(x[2*c+1].w);
                const unsigned byte = (unsigned)(rk * 128 + 64 * hk + 16 * c);
                *(bf16x8*)((char*)Klds + (byte ^ rswz)) = kb;
            }
        }
        if (2 * kp < kwidth) {
            const float* s0 = Vp + (size_t)(kvb + 2 * kp) * DH + 16 * dq;
            float av[16], bv[16];
            #pragma unroll
            for (int i = 0; i < 4; ++i) {
                float4 ta = *reinterpret_cast<const float4*>(s0 + 4 * i);
                float4 tb = *reinterpret_cast<const float4*>(s0 + DH + 4 * i);
                av[4*i]=ta.x; av[4*i+1]=ta.y; av[4*i+2]=ta.z; av[4*i+3]=ta.w;
                bv[4*i]=tb.x; bv[4*i+1]=tb.y; bv[4*i+2]=tb.z; bv[4*i+3]=tb.w;
            }
            #pragma unroll
            for (int j = 0; j < 16; ++j) {
                const int d = 16 * dq + j;
                const unsigned byte = (unsigned)(d * 256 + 4 * kp);
                *(unsigned*)((char*)Vlds + (byte ^ (((unsigned)(d & 7)) << 4))) =
                    pk2(av[j], bv[j]);
            }
        }
        __syncthreads();

        f32x4 s[8];
        #pragma unroll
        for (int t = 0; t < 8; ++t) {
            if (16 * t < kwidth) {
                s[t] = (f32x4){0.f, 0.f, 0.f, 0.f};
                #pragma unroll
                for (int c = 0; c < 2; ++c) {
                    const unsigned row  = (unsigned)(16 * t + m);
                    const unsigned byte =
                        (row * 128u + (unsigned)(32 * c + 8 * g) * 2u) ^ ((row & 7u) << 4);
                    bf16x8 kf = *(const bf16x8*)((const char*)Klds + byte);
                    s[t] = __builtin_amdgcn_mfma_f32_16x16x32_bf16(kf, qf[c], s[t], 0, 0, 0);
                }
            }
        }

        float mx = -1e30f;
        #pragma unroll
        for (int t = 0; t < 8; ++t) {
            if (16 * t < kwidth) {
                #pragma unroll
                for (int r = 0; r < 4; ++r) {
                    float v = s[t][r];
                    if (last) {
                        const int kk = kvb + 16 * t + 4 * g + r;
                        v = (kk > q) ? -1e30f : v;
                    }
                    s[t][r] = v;
                    mx = fmaxf(mx, v);
                }
            }
        }
        mx = fmaxf(mx, __shfl_xor(mx, 16));
        mx = fmaxf(mx, __shfl_xor(mx, 32));
        const float mnew = fmaxf(mrun, mx);
        const float fs   = exp2f(mrun - mnew);
        mrun = mnew;

        float psum = 0.f;
        #pragma unroll
        for (int t = 0; t < 8; ++t) {
            if (16 * t < kwidth) {
                const float p0 = exp2f(s[t][0] - mnew);
                const float p1 = exp2f(s[t][1] - mnew);
                const float p2 = exp2f(s[t][2] - mnew);
                const float p3 = exp2f(s[t][3] - mnew);
                psum += (p0 + p1) + (p2 + p3);
                uint2 e;
                e.x = pk2(p0, p1);
                e.y = pk2(p2, p3);
                const unsigned byte = (unsigned)(m * 256 + 32 * t + 8 * g);
                *(uint2*)(Pw + (byte ^ pswz)) = e;
            }
        }
        psum += __shfl_xor(psum, 16);
        psum += __shfl_xor(psum, 32);
        lrun = lrun * fs + psum;

        float fso[4];
        #pragma unroll
        for (int r = 0; r < 4; ++r)
            fso[r] = __shfl(fs, (lane & 48) | (4 * g + r));
        #pragma unroll
        for (int dt = 0; dt < 4; ++dt) {
            #pragma unroll
            for (int r = 0; r < 4; ++r) o[dt][r] *= fso[r];
        }

        const int kclim = kwidth >> 5;
        #pragma unroll
        for (int kc = 0; kc < 4; ++kc) {
            if (kc < kclim) {
                const unsigned ab = ((unsigned)(m * 256 + 64 * kc + 16 * g)) ^ pswz;
                bf16x8 pa = *(const bf16x8*)(Pw + ab);
                #pragma unroll
                for (int dt = 0; dt < 4; ++dt) {
                    const unsigned d  = (unsigned)(16 * dt + m);
                    const unsigned vby =
                        (d * 256u + (unsigned)(64 * kc + 16 * g)) ^ ((d & 7u) << 4);
                    bf16x8 vf = *(const bf16x8*)((const char*)Vlds + vby);
                    o[dt] = __builtin_amdgcn_mfma_f32_16x16x32_bf16(pa, vf, o[dt], 0, 0, 0);
                }
            }
        }
        __syncthreads();
    }

    const float invl = 1.0f / lrun;
    float invo[4];
    #pragma unroll
    for (int r = 0; r < 4; ++r)
        invo[r] = __shfl(invl, (lane & 48) | (4 * g + r));
    #pragma unroll
    for (int r = 0; r < 4; ++r) {
        const int qrow = qb + 16 * w + 4 * g + r;
        float* dst = Op + (size_t)qrow * DH;
        #pragma unroll
        for (int dt = 0; dt < 4; ++dt) dst[16 * dt + m] = o[dt][r] * invo[r];
    }
}

extern "C" void kernel_launch(void* const* d_in, const int* in_sizes, int n_in,
                              void* d_out, int out_size, void* d_ws, size_t ws_size,
                              hipStream_t stream) {
    const float* Q = (const float*)d_in[0];
    const float* K = (const float*)d_in[1];
    const float* V = (const float*)d_in[2];
    float* O = (float*)d_out;
    if (ws_size >= 2 * VPRE_OFF) {
        unsigned short* ws = (unsigned short*)d_ws;
        prep<<<dim3(3072), dim3(256), 0, stream>>>(K, V, ws);
        fattn_f<<<dim3(1024), dim3(256), 0, stream>>>(Q, ws, O);
    } else {
        fattn_s<<<dim3(1024), dim3(256), 0, stream>>>(Q, K, V, O);
    }
}

// Round 7
// 153.863 us; speedup vs baseline: 1.9258x; 1.0282x over previous
//
#include <hip/hip_runtime.h>
#include <hip/hip_bf16.h>
#include <cstdint>
#include <cstddef>

#define SLEN 2048
#define DH   64
#define NQT  32          // SLEN / QBLK
#define QBLK 64
#define KVB  64          // fast-path kv tile
#define NHEADS 32        // B*H
#define LOG2E 1.44269504088896340736f

#define PRE_HEAD_BYTES (SLEN * DH * 2)          // 262144 per head (bf16)
#define TILE_BYTES     (KVB * DH * 2)           // 8192 per 64-row tile
#define VPRE_OFF       ((size_t)NHEADS * PRE_HEAD_BYTES)   // 8 MiB

typedef short  bf16x8 __attribute__((ext_vector_type(8)));
typedef float  f32x4  __attribute__((ext_vector_type(4)));

__device__ __forceinline__ unsigned short f2bf(float f) {
    __hip_bfloat16 h = __float2bfloat16(f);
    return *reinterpret_cast<unsigned short*>(&h);
}
__device__ __forceinline__ unsigned int pk2(float a, float b) {
    return (unsigned int)f2bf(a) | ((unsigned int)f2bf(b) << 16);
}

#define GLL(gp, lp)                                                            \
    __builtin_amdgcn_global_load_lds(                                          \
        (const __attribute__((address_space(1))) void*)(gp),                   \
        (__attribute__((address_space(3))) void*)(lp), 16, 0, 0)

// ---------------------------------------------------------------------------
// Prep: K -> bf16 [k][d] rows (swizzled LDS image), V -> bf16 transposed
// [d][k] per 64-k tile (swizzled image). Validated round 6 (~20 us).
// ---------------------------------------------------------------------------
__global__ __launch_bounds__(256) void prep(const float* __restrict__ Kg,
                                            const float* __restrict__ Vg,
                                            unsigned short* __restrict__ ws)
{
    const int bid = blockIdx.x;
    const int tid = threadIdx.x;
    if (bid < 2048) {
        // ---- K: one 16B bf16 chunk per thread, coalesced both sides ----
        const int cid = bid * 256 + tid;
        const int h   = cid >> 14;             // 16384 chunks / head
        const int rem = cid & 16383;
        const int r   = rem >> 3;              // row 0..2047
        const int ccs = rem & 7;               // stored d-chunk
        const int d0  = 8 * (ccs ^ (r & 7));   // swizzle involution
        const float* src = Kg + ((size_t)h * SLEN + r) * DH + d0;
        float4 a = *reinterpret_cast<const float4*>(src);
        float4 b = *reinterpret_cast<const float4*>(src + 4);
        bf16x8 o;
        o[0]=(short)f2bf(a.x); o[1]=(short)f2bf(a.y);
        o[2]=(short)f2bf(a.z); o[3]=(short)f2bf(a.w);
        o[4]=(short)f2bf(b.x); o[5]=(short)f2bf(b.y);
        o[6]=(short)f2bf(b.z); o[7]=(short)f2bf(b.w);
        *(bf16x8*)((char*)ws + (size_t)cid * 16) = o;
    } else {
        // ---- V: one 64k x 64d tile per block, transpose via LDS ----
        __shared__ __attribute__((aligned(16))) unsigned short Vt[KVB * DH];
        const int vb = bid - 2048;
        const int h  = vb >> 5;
        const int t  = vb & 31;
        const int do8 = tid & 7;               // d-octet
        const int kp  = tid >> 3;              // k-pair
        const float* s0 = Vg + ((size_t)h * SLEN + (size_t)t * KVB + 2 * kp) * DH + 8 * do8;
        float4 a0 = *reinterpret_cast<const float4*>(s0);
        float4 a1 = *reinterpret_cast<const float4*>(s0 + 4);
        float4 b0 = *reinterpret_cast<const float4*>(s0 + DH);
        float4 b1 = *reinterpret_cast<const float4*>(s0 + DH + 4);
        float av[8] = {a0.x,a0.y,a0.z,a0.w,a1.x,a1.y,a1.z,a1.w};
        float bv[8] = {b0.x,b0.y,b0.z,b0.w,b1.x,b1.y,b1.z,b1.w};
        #pragma unroll
        for (int j = 0; j < 8; ++j) {
            const int d = 8 * do8 + j;
            const unsigned byte =
                ((unsigned)(d * 128 + 4 * kp)) ^ (((unsigned)(d & 7)) << 4);
            *(unsigned*)((char*)Vt + byte) = pk2(av[j], bv[j]);
        }
        __syncthreads();
        char* gdst = (char*)ws + VPRE_OFF + (size_t)h * PRE_HEAD_BYTES
                   + (size_t)t * TILE_BYTES + (size_t)tid * 32;
        const char* lsrc = (const char*)Vt + tid * 32;
        *(bf16x8*)(gdst)      = *(const bf16x8*)(lsrc);
        *(bf16x8*)(gdst + 16) = *(const bf16x8*)(lsrc + 16);
    }
}

// ---------------------------------------------------------------------------
// Fast attention. Triple-buffered K/V staged 2 tiles ahead via
// global_load_lds; counted vmcnt(4) before each raw s_barrier (T3/T4 —
// each wave waits its OWN loads before the barrier gating first use, so
// next-next tile's loads stay in flight across barriers). 56 KB LDS ->
// 2 blocks/CU, grid 1024 -> backfill queue; longest blocks dispatch first.
// ---------------------------------------------------------------------------
__global__ __launch_bounds__(256, 2) void fattn_f(const float* __restrict__ Qg,
                                                  const unsigned short* __restrict__ KV,
                                                  float* __restrict__ Og)
{
    __shared__ __attribute__((aligned(16))) unsigned short Klds[3][KVB * DH];
    __shared__ __attribute__((aligned(16))) unsigned short Vlds[3][DH * KVB];
    __shared__ __attribute__((aligned(16))) unsigned short Plds[4][16 * KVB];

    const int bid = blockIdx.x;
    const int qt  = 31 - (bid >> 5);   // longest-first dispatch (LPT)
    const int bh  = bid & 31;
    const int qb  = qt * QBLK;

    const float* Qp   = Qg + (size_t)bh * SLEN * DH;
    const char*  Kpre = (const char*)KV + (size_t)bh * PRE_HEAD_BYTES;
    const char*  Vpre = (const char*)KV + VPRE_OFF + (size_t)bh * PRE_HEAD_BYTES;
    float*       Op   = Og + (size_t)bh * SLEN * DH;

    const int tid  = threadIdx.x;
    const int w    = tid >> 6;
    const int lane = tid & 63;
    const int g    = lane >> 4;
    const int m    = lane & 15;

    // ---- Q fragments (B operand): lane(g,m) = Q[qb+16w+m][32c+8g+j] ----
    bf16x8 qf[2];
    {
        const float sc = 0.125f * LOG2E;
        const int qrow = qb + 16 * w + m;
        #pragma unroll
        for (int c = 0; c < 2; ++c) {
            const float* src = Qp + (size_t)qrow * DH + 32 * c + 8 * g;
            float4 a = *reinterpret_cast<const float4*>(src);
            float4 b = *reinterpret_cast<const float4*>(src + 4);
            bf16x8 qv;
            qv[0]=(short)f2bf(a.x*sc); qv[1]=(short)f2bf(a.y*sc);
            qv[2]=(short)f2bf(a.z*sc); qv[3]=(short)f2bf(a.w*sc);
            qv[4]=(short)f2bf(b.x*sc); qv[5]=(short)f2bf(b.y*sc);
            qv[6]=(short)f2bf(b.z*sc); qv[7]=(short)f2bf(b.w*sc);
            qf[c] = qv;
        }
    }

    f32x4 o[4];
    #pragma unroll
    for (int dt = 0; dt < 4; ++dt) o[dt] = (f32x4){0.f, 0.f, 0.f, 0.f};
    float mrun = -1e30f, lrun = 0.f;   // per-lane stats for q-row = m

    const int nt = qt + 1;             // 64-wide tiles

    char* Pw = (char*)&Plds[w][0];
    const unsigned pswz = ((unsigned)(m & 7)) << 4;
    const int q = qb + 16 * w + m;

    // ---- staging: 4x global_load_lds dwordx4 (pre-swizzled src, linear dst)
    #define STAGE(jt_, b_)                                                     \
        do {                                                                   \
            const char* gk_ = Kpre + (size_t)(jt_) * TILE_BYTES + tid * 16;    \
            const char* gv_ = Vpre + (size_t)(jt_) * TILE_BYTES + tid * 16;    \
            char* lk_ = (char*)Klds + (size_t)(b_) * TILE_BYTES + tid * 16;    \
            char* lv_ = (char*)Vlds + (size_t)(b_) * TILE_BYTES + tid * 16;    \
            GLL(gk_,        lk_);                                              \
            GLL(gk_ + 4096, lk_ + 4096);                                       \
            GLL(gv_,        lv_);                                              \
            GLL(gv_ + 4096, lv_ + 4096);                                       \
        } while (0)

    int c0 = 0, c1 = 1, c2 = 2;        // current / next / stage-target
    STAGE(0, 0);
    if (nt > 1) {
        STAGE(1, 1);
        asm volatile("s_waitcnt vmcnt(4)" ::: "memory");   // tile0 landed
    } else {
        asm volatile("s_waitcnt vmcnt(0)" ::: "memory");
    }
    __builtin_amdgcn_s_barrier();

    for (int jt = 0; jt < nt; ++jt) {
        const int kvb   = jt * KVB;
        const bool last = (jt == nt - 1);
        const bool more = (jt + 2 < nt);

        if (more) STAGE(jt + 2, c2);   // 2-ahead: two compute phases to land

        const char* Kb = (const char*)Klds + (size_t)c0 * TILE_BYTES;
        const char* Vb = (const char*)Vlds + (size_t)c0 * TILE_BYTES;

        // ---- QK^T swapped: s[t] rows k=16t+4g+r, col q=m ----
        f32x4 s[4];
        __builtin_amdgcn_s_setprio(1);
        #pragma unroll
        for (int t = 0; t < 4; ++t) {
            s[t] = (f32x4){0.f, 0.f, 0.f, 0.f};
            #pragma unroll
            for (int c = 0; c < 2; ++c) {
                const unsigned row  = (unsigned)(16 * t + m);
                const unsigned byte =
                    (row * 128u + (unsigned)(32 * c + 8 * g) * 2u) ^ ((row & 7u) << 4);
                bf16x8 kf = *(const bf16x8*)(Kb + byte);
                s[t] = __builtin_amdgcn_mfma_f32_16x16x32_bf16(kf, qf[c], s[t], 0, 0, 0);
            }
        }
        __builtin_amdgcn_s_setprio(0);

        // ---- softmax: row q=m lane-local; 2 butterflies over g ----
        float mx = -1e30f;
        #pragma unroll
        for (int t = 0; t < 4; ++t) {
            #pragma unroll
            for (int r = 0; r < 4; ++r) {
                float v = s[t][r];
                if (last) {
                    const int kk = kvb + 16 * t + 4 * g + r;
                    v = (kk > q) ? -1e30f : v;
                }
                s[t][r] = v;
                mx = fmaxf(mx, v);
            }
        }
        mx = fmaxf(mx, __shfl_xor(mx, 16));
        mx = fmaxf(mx, __shfl_xor(mx, 32));

        // T13 defer-rescale, THR=0 (numerically identical): only rescale
        // when some row's max actually grew. Uniform branch via __any.
        if (__any(mx > mrun)) {
            const float mnew = fmaxf(mrun, mx);
            const float fs   = exp2f(mrun - mnew);
            mrun = mnew;
            lrun *= fs;
            float fso[4];
            #pragma unroll
            for (int r = 0; r < 4; ++r)
                fso[r] = __shfl(fs, (lane & 48) | (4 * g + r));
            #pragma unroll
            for (int dt = 0; dt < 4; ++dt) {
                #pragma unroll
                for (int r = 0; r < 4; ++r) o[dt][r] *= fso[r];
            }
        }

        float psum = 0.f;
        #pragma unroll
        for (int t = 0; t < 4; ++t) {
            const float p0 = exp2f(s[t][0] - mrun);
            const float p1 = exp2f(s[t][1] - mrun);
            const float p2 = exp2f(s[t][2] - mrun);
            const float p3 = exp2f(s[t][3] - mrun);
            psum += (p0 + p1) + (p2 + p3);
            uint2 e;
            e.x = pk2(p0, p1);
            e.y = pk2(p2, p3);
            const unsigned byte = (unsigned)(m * 128 + 32 * t + 8 * g);
            *(uint2*)(Pw + (byte ^ pswz)) = e;   // same-wave DS in-order
        }
        psum += __shfl_xor(psum, 16);
        psum += __shfl_xor(psum, 32);
        lrun += psum;

        // ---- PV: O[16q x 64d] += P[16 x 64] * V[64 x 64] ----
        __builtin_amdgcn_s_setprio(1);
        #pragma unroll
        for (int kc = 0; kc < 2; ++kc) {
            const unsigned ab = ((unsigned)(m * 128 + 64 * kc + 16 * g)) ^ pswz;
            bf16x8 pa = *(const bf16x8*)(Pw + ab);
            #pragma unroll
            for (int dt = 0; dt < 4; ++dt) {
                const unsigned d  = (unsigned)(16 * dt + m);
                const unsigned vby =
                    (d * 128u + (unsigned)(64 * kc + 16 * g)) ^ ((d & 7u) << 4);
                bf16x8 vf = *(const bf16x8*)(Vb + vby);
                o[dt] = __builtin_amdgcn_mfma_f32_16x16x32_bf16(pa, vf, o[dt], 0, 0, 0);
            }
        }
        __builtin_amdgcn_s_setprio(0);

        // ---- counted wait BEFORE barrier: tile jt+1's loads (issued at
        // iter jt-1) must be landed; tile jt+2's (issued above) may fly. ----
        if (more) asm volatile("s_waitcnt vmcnt(4)" ::: "memory");
        else      asm volatile("s_waitcnt vmcnt(0)" ::: "memory");
        __builtin_amdgcn_s_barrier();

        const int tswap = c0; c0 = c1; c1 = c2; c2 = tswap;   // rotate buffers
    }
    #undef STAGE

    // ---- epilogue ----
    const float invl = 1.0f / lrun;
    float invo[4];
    #pragma unroll
    for (int r = 0; r < 4; ++r)
        invo[r] = __shfl(invl, (lane & 48) | (4 * g + r));
    #pragma unroll
    for (int r = 0; r < 4; ++r) {
        const int qrow = qb + 16 * w + 4 * g + r;
        float* dst = Op + (size_t)qrow * DH;
        #pragma unroll
        for (int dt = 0; dt < 4; ++dt) dst[16 * dt + m] = o[dt][r] * invo[r];
    }
}

// ---------------------------------------------------------------------------
// Fallback (validated round-4 kernel, KVB=128 inline) if ws too small.
// ---------------------------------------------------------------------------
__global__ __launch_bounds__(256, 4) void fattn_s(const float* __restrict__ Qg,
                                                  const float* __restrict__ Kg,
                                                  const float* __restrict__ Vg,
                                                  float* __restrict__ Og)
{
    __shared__ __attribute__((aligned(16))) unsigned short Klds[128 * DH];
    __shared__ __attribute__((aligned(16))) unsigned short Vlds[DH * 128];
    __shared__ __attribute__((aligned(16))) unsigned short Plds[4][16 * 128];

    const int bid = blockIdx.x;
    const int hi4 = bid >> 8;
    const int lo8 = bid & 255;
    const int qx  = (int)((0x0F101F00u >> (8 * hi4)) & 31u);
    const int qt  = (lo8 & 31) ^ qx;
    const int bh  = (hi4 << 3) | (lo8 >> 5);
    const int qb  = qt * QBLK;

    const float* Qp = Qg + (size_t)bh * SLEN * DH;
    const float* Kp = Kg + (size_t)bh * SLEN * DH;
    const float* Vp = Vg + (size_t)bh * SLEN * DH;
    float*       Op = Og + (size_t)bh * SLEN * DH;

    const int tid  = threadIdx.x;
    const int w    = tid >> 6;
    const int lane = tid & 63;
    const int g    = lane >> 4;
    const int m    = lane & 15;

    bf16x8 qf[2];
    {
        const float sc = 0.125f * LOG2E;
        const int qrow = qb + 16 * w + m;
        #pragma unroll
        for (int c = 0; c < 2; ++c) {
            const float* src = Qp + (size_t)qrow * DH + 32 * c + 8 * g;
            float4 a = *reinterpret_cast<const float4*>(src);
            float4 b = *reinterpret_cast<const float4*>(src + 4);
            bf16x8 qv;
            qv[0]=(short)f2bf(a.x*sc); qv[1]=(short)f2bf(a.y*sc);
            qv[2]=(short)f2bf(a.z*sc); qv[3]=(short)f2bf(a.w*sc);
            qv[4]=(short)f2bf(b.x*sc); qv[5]=(short)f2bf(b.y*sc);
            qv[6]=(short)f2bf(b.z*sc); qv[7]=(short)f2bf(b.w*sc);
            qf[c] = qv;
        }
    }

    f32x4 o[4];
    #pragma unroll
    for (int dt = 0; dt < 4; ++dt) o[dt] = (f32x4){0.f, 0.f, 0.f, 0.f};
    float mrun = -1e30f, lrun = 0.f;

    const int klim = qb + QBLK;
    const int nt   = (qt + 2) >> 1;

    const int rk = tid & 127, hk = tid >> 7;
    const int kp = tid & 63,  dq = tid >> 6;

    char* Pw = (char*)&Plds[w][0];
    const unsigned pswz = ((unsigned)(m & 7)) << 4;
    const int q = qb + 16 * w + m;

    for (int jt = 0; jt < nt; ++jt) {
        const int kvb    = jt * 128;
        const int kwidth = min(128, klim - kvb);
        const bool last  = (jt == nt - 1);

        if (rk < kwidth) {
            const float4* s4 = reinterpret_cast<const float4*>(
                Kp + (size_t)(kvb + rk) * DH + 32 * hk);
            float4 x[8];
            #pragma unroll
            for (int i = 0; i < 8; ++i) x[i] = s4[i];
            const unsigned rswz = ((unsigned)(rk & 7)) << 4;
            #pragma unroll
            for (int c = 0; c < 4; ++c) {
                bf16x8 kb;
                kb[0]=(short)f2bf(x[2*c].x);   kb[1]=(short)f2bf(x[2*c].y);
                kb[2]=(short)f2bf(x[2*c].z);   kb[3]=(short)f2bf(x[2*c].w);
                kb[4]=(short)f2bf(x[2*c+1].x); kb[5]=(short)f2bf(x[2*c+1].y);
                kb[6]=(short)f2bf(x[2*c+1].z); kb[7]=(short)f2bf(x[2*c+1].w);
                const unsigned byte = (unsigned)(rk * 128 + 64 * hk + 16 * c);
                *(bf16x8*)((char*)Klds + (byte ^ rswz)) = kb;
            }
        }
        if (2 * kp < kwidth) {
            const float* s0 = Vp + (size_t)(kvb + 2 * kp) * DH + 16 * dq;
            float av[16], bv[16];
            #pragma unroll
            for (int i = 0; i < 4; ++i) {
                float4 ta = *reinterpret_cast<const float4*>(s0 + 4 * i);
                float4 tb = *reinterpret_cast<const float4*>(s0 + DH + 4 * i);
                av[4*i]=ta.x; av[4*i+1]=ta.y; av[4*i+2]=ta.z; av[4*i+3]=ta.w;
                bv[4*i]=tb.x; bv[4*i+1]=tb.y; bv[4*i+2]=tb.z; bv[4*i+3]=tb.w;
            }
            #pragma unroll
            for (int j = 0; j < 16; ++j) {
                const int d = 16 * dq + j;
                const unsigned byte = (unsigned)(d * 256 + 4 * kp);
                *(unsigned*)((char*)Vlds + (byte ^ (((unsigned)(d & 7)) << 4))) =
                    pk2(av[j], bv[j]);
            }
        }
        __syncthreads();

        f32x4 s[8];
        #pragma unroll
        for (int t = 0; t < 8; ++t) {
            if (16 * t < kwidth) {
                s[t] = (f32x4){0.f, 0.f, 0.f, 0.f};
                #pragma unroll
                for (int c = 0; c < 2; ++c) {
                    const unsigned row  = (unsigned)(16 * t + m);
                    const unsigned byte =
                        (row * 128u + (unsigned)(32 * c + 8 * g) * 2u) ^ ((row & 7u) << 4);
                    bf16x8 kf = *(const bf16x8*)((const char*)Klds + byte);
                    s[t] = __builtin_amdgcn_mfma_f32_16x16x32_bf16(kf, qf[c], s[t], 0, 0, 0);
                }
            }
        }

        float mx = -1e30f;
        #pragma unroll
        for (int t = 0; t < 8; ++t) {
            if (16 * t < kwidth) {
                #pragma unroll
                for (int r = 0; r < 4; ++r) {
                    float v = s[t][r];
                    if (last) {
                        const int kk = kvb + 16 * t + 4 * g + r;
                        v = (kk > q) ? -1e30f : v;
                    }
                    s[t][r] = v;
                    mx = fmaxf(mx, v);
                }
            }
        }
        mx = fmaxf(mx, __shfl_xor(mx, 16));
        mx = fmaxf(mx, __shfl_xor(mx, 32));
        const float mnew = fmaxf(mrun, mx);
        const float fs   = exp2f(mrun - mnew);
        mrun = mnew;

        float psum = 0.f;
        #pragma unroll
        for (int t = 0; t < 8; ++t) {
            if (16 * t < kwidth) {
                const float p0 = exp2f(s[t][0] - mnew);
                const float p1 = exp2f(s[t][1] - mnew);
                const float p2 = exp2f(s[t][2] - mnew);
                const float p3 = exp2f(s[t][3] - mnew);
                psum += (p0 + p1) + (p2 + p3);
                uint2 e;
                e.x = pk2(p0, p1);
                e.y = pk2(p2, p3);
                const unsigned byte = (unsigned)(m * 256 + 32 * t + 8 * g);
                *(uint2*)(Pw + (byte ^ pswz)) = e;
            }
        }
        psum += __shfl_xor(psum, 16);
        psum += __shfl_xor(psum, 32);
        lrun = lrun * fs + psum;

        float fso[4];
        #pragma unroll
        for (int r = 0; r < 4; ++r)
            fso[r] = __shfl(fs, (lane & 48) | (4 * g + r));
        #pragma unroll
        for (int dt = 0; dt < 4; ++dt) {
            #pragma unroll
            for (int r = 0; r < 4; ++r) o[dt][r] *= fso[r];
        }

        const int kclim = kwidth >> 5;
        #pragma unroll
        for (int kc = 0; kc < 4; ++kc) {
            if (kc < kclim) {
                const unsigned ab = ((unsigned)(m * 256 + 64 * kc + 16 * g)) ^ pswz;
                bf16x8 pa = *(const bf16x8*)(Pw + ab);
                #pragma unroll
                for (int dt = 0; dt < 4; ++dt) {
                    const unsigned d  = (unsigned)(16 * dt + m);
                    const unsigned vby =
                        (d * 256u + (unsigned)(64 * kc + 16 * g)) ^ ((d & 7u) << 4);
                    bf16x8 vf = *(const bf16x8*)((const char*)Vlds + vby);
                    o[dt] = __builtin_amdgcn_mfma_f32_16x16x32_bf16(pa, vf, o[dt], 0, 0, 0);
                }
            }
        }
        __syncthreads();
    }

    const float invl = 1.0f / lrun;
    float invo[4];
    #pragma unroll
    for (int r = 0; r < 4; ++r)
        invo[r] = __shfl(invl, (lane & 48) | (4 * g + r));
    #pragma unroll
    for (int r = 0; r < 4; ++r) {
        const int qrow = qb + 16 * w + 4 * g + r;
        float* dst = Op + (size_t)qrow * DH;
        #pragma unroll
        for (int dt = 0; dt < 4; ++dt) dst[16 * dt + m] = o[dt][r] * invo[r];
    }
}

extern "C" void kernel_launch(void* const* d_in, const int* in_sizes, int n_in,
                              void* d_out, int out_size, void* d_ws, size_t ws_size,
                              hipStream_t stream) {
    const float* Q = (const float*)d_in[0];
    const float* K = (const float*)d_in[1];
    const float* V = (const float*)d_in[2];
    float* O = (float*)d_out;
    if (ws_size >= 2 * VPRE_OFF) {
        unsigned short* ws = (unsigned short*)d_ws;
        prep<<<dim3(3072), dim3(256), 0, stream>>>(K, V, ws);
        fattn_f<<<dim3(1024), dim3(256), 0, stream>>>(Q, ws, O);
    } else {
        fattn_s<<<dim3(1024), dim3(256), 0, stream>>>(Q, K, V, O);
    }
}